// Round 1
// baseline (455.162 us; speedup 1.0000x reference)
//
#include <hip/hip_runtime.h>
#include <math.h>

#define B_ 16
#define C_ 512
#define P_ 256
#define G_ 8
#define PG_ 32   // planes per group (P/G)
#define OG_ 64   // out channels per group (C/G)
#define HW1 4096
#define HW2 1024
#define EPS_ 1e-5f

// ---------------------------------------------------------------------------
// K1: fused p/g projection + Taylor reductions.
// grid 1024 = (b:16, g:8, hwt:8), 256 threads.
// Block computes pg,gg for [32 planes][128 hw2] via tiled dot over C=512,
// then reduces S0 = sum(g), S1 = sum(p*g), S2 = sum(p^2*g) -> partial per block.
// beta decode puts hwt in beta&7 so all 8 g-blocks of a tile share an XCD.
// ---------------------------------------------------------------------------
__global__ __launch_bounds__(256)
void k1_att(const float* __restrict__ xlo, const float* __restrict__ Wp,
            const float* __restrict__ Wg, float* __restrict__ att_part)
{
    __shared__ float sX[32][128];
    __shared__ float sWp[32][32];
    __shared__ float sWg[32][32];
    __shared__ float sred[3 * 256];

    int beta = blockIdx.x;
    int hwt = beta & 7, g = (beta >> 3) & 7, b = beta >> 6;
    int hw0 = hwt * 128;
    int tid = threadIdx.x;
    int to = tid >> 5, th = tid & 31;   // thread tile [4 o][4 hw]

    const float* xb = xlo + (size_t)b * C_ * HW2 + hw0;
    const float* wp = Wp + (size_t)(g * PG_) * C_;
    const float* wg = Wg + (size_t)(g * PG_) * C_;

    float pa[4][4] = {}, ga[4][4] = {};

    for (int c0 = 0; c0 < C_; c0 += 32) {
        __syncthreads();
        {
            int col = (tid & 31) * 4;
            int r0 = tid >> 5;
#pragma unroll
            for (int i = 0; i < 4; i++) {
                int r = r0 + 8 * i;
                *(float4*)&sX[r][col] =
                    *(const float4*)&xb[(size_t)(c0 + r) * HW2 + col];
            }
            int o = tid >> 3, cc4 = (tid & 7) * 4;
            *(float4*)&sWp[o][cc4] = *(const float4*)&wp[(size_t)o * C_ + c0 + cc4];
            *(float4*)&sWg[o][cc4] = *(const float4*)&wg[(size_t)o * C_ + c0 + cc4];
        }
        __syncthreads();
#pragma unroll
        for (int cc = 0; cc < 32; cc++) {
            float4 xv = *(const float4*)&sX[cc][th * 4];
#pragma unroll
            for (int j = 0; j < 4; j++) {
                float wpv = sWp[to * 4 + j][cc];
                float wgv = sWg[to * 4 + j][cc];
                pa[j][0] += wpv * xv.x; pa[j][1] += wpv * xv.y;
                pa[j][2] += wpv * xv.z; pa[j][3] += wpv * xv.w;
                ga[j][0] += wgv * xv.x; ga[j][1] += wgv * xv.y;
                ga[j][2] += wgv * xv.z; ga[j][3] += wgv * xv.w;
            }
        }
    }

    float s0 = 0, s1 = 0, s2 = 0;
#pragma unroll
    for (int j = 0; j < 4; j++)
#pragma unroll
        for (int k = 0; k < 4; k++) {
            float pv = pa[j][k], gv = ga[j][k];
            s0 += gv; s1 += pv * gv; s2 += pv * pv * gv;
        }
    __syncthreads();
    sred[tid] = s0; sred[256 + tid] = s1; sred[512 + tid] = s2;
    __syncthreads();
    for (int off = 128; off > 0; off >>= 1) {
        if (tid < off) {
            sred[tid] += sred[tid + off];
            sred[256 + tid] += sred[256 + tid + off];
            sred[512 + tid] += sred[512 + tid + off];
        }
        __syncthreads();
    }
    if (tid == 0) {
        float* dst = att_part + (size_t)((b * G_ + g) * 8 + hwt) * 3;
        dst[0] = sred[0]; dst[1] = sred[256]; dst[2] = sred[512];
    }
}

// Reduce tile partials -> c_k = alpha_k^2 * S_k per (b,g)
__global__ void k1b_coef(const float* __restrict__ att_part, float* __restrict__ coef,
                         float a0s, float a1s, float a2s)
{
    int t = threadIdx.x;
    if (t >= 128) return;
    float S0 = 0, S1 = 0, S2 = 0;
    const float* p = att_part + (size_t)t * 8 * 3;
    for (int i = 0; i < 8; i++) { S0 += p[i * 3]; S1 += p[i * 3 + 1]; S2 += p[i * 3 + 2]; }
    coef[t * 3 + 0] = a0s * S0;
    coef[t * 3 + 1] = a1s * S1;
    coef[t * 3 + 2] = a2s * S2;
}

// ---------------------------------------------------------------------------
// K2: fused t-GEMM -> polynomial -> grouped 1x1 conv (z) + GN partial stats.
// grid 4096 = (b:16, hwh:2b, g:8, x:3b), 256 threads. hwt = hwh*8 + x.
// beta&7 == x so the 8 g-blocks of one (b,hwt) input slice share an XCD L2.
// Phase1: tt[32 p][128 hw] = Wt_g @ x_hi  (K=512, chunks of 32 via LDS)
// Phase2: xx = c1*tt + c2*tt^2 into LDS
// Phase3: z[64 o][128 hw] = Wz_g @ xx + c0*rowsum(Wz_g); write z to d_out,
//         accumulate block partials of sum(z), sum(z^2).
// ---------------------------------------------------------------------------
__global__ __launch_bounds__(256)
void k2_main(const float* __restrict__ xhi, const float* __restrict__ Wt,
             const float* __restrict__ Wz, const float* __restrict__ coef,
             float* __restrict__ zout, float* __restrict__ zstat_part)
{
    __shared__ float sBuf[32][128];
    __shared__ float sWt[32][32];
    __shared__ float sWz[64 * 32];
    __shared__ float sSw[64];
    __shared__ float sred[2 * 256];

    int beta = blockIdx.x;
    int x = beta & 7;
    int g = (beta >> 3) & 7;
    int hwh = (beta >> 6) & 3;
    int b = beta >> 8;
    int hwt = hwh * 8 + x;
    int hw0 = hwt * 128;
    int tid = threadIdx.x;

    const float* cf = coef + (size_t)(b * G_ + g) * 3;
    float c0v = cf[0], c1v = cf[1], c2v = cf[2];

    {   // stage Wz group block (64x32) once
        const float* wzg = Wz + (size_t)g * OG_ * PG_;
        *(float4*)&sWz[tid * 8]     = *(const float4*)&wzg[tid * 8];
        *(float4*)&sWz[tid * 8 + 4] = *(const float4*)&wzg[tid * 8 + 4];
    }

    // ---- Phase 1: t GEMM ----
    int to = tid >> 5, th = tid & 31;
    const float* xb = xhi + (size_t)b * C_ * HW1 + hw0;
    const float* wt = Wt + (size_t)(g * PG_) * C_;
    float ta[4][4] = {};
    for (int c0 = 0; c0 < C_; c0 += 32) {
        __syncthreads();
        {
            int col = (tid & 31) * 4;
            int r0 = tid >> 5;
#pragma unroll
            for (int i = 0; i < 4; i++) {
                int r = r0 + 8 * i;
                *(float4*)&sBuf[r][col] =
                    *(const float4*)&xb[(size_t)(c0 + r) * HW1 + col];
            }
            int o = tid >> 3, cc4 = (tid & 7) * 4;
            *(float4*)&sWt[o][cc4] = *(const float4*)&wt[(size_t)o * C_ + c0 + cc4];
        }
        __syncthreads();
#pragma unroll
        for (int cc = 0; cc < 32; cc++) {
            float4 xv = *(const float4*)&sBuf[cc][th * 4];
#pragma unroll
            for (int j = 0; j < 4; j++) {
                float w = sWt[to * 4 + j][cc];
                ta[j][0] += w * xv.x; ta[j][1] += w * xv.y;
                ta[j][2] += w * xv.z; ta[j][3] += w * xv.w;
            }
        }
    }
    __syncthreads();

    // ---- Phase 2: xx = c1*t + c2*t^2 ----
#pragma unroll
    for (int j = 0; j < 4; j++) {
        float4 v;
        v.x = c1v * ta[j][0] + c2v * ta[j][0] * ta[j][0];
        v.y = c1v * ta[j][1] + c2v * ta[j][1] * ta[j][1];
        v.z = c1v * ta[j][2] + c2v * ta[j][2] * ta[j][2];
        v.w = c1v * ta[j][3] + c2v * ta[j][3] * ta[j][3];
        *(float4*)&sBuf[to * 4 + j][th * 4] = v;
    }
    __syncthreads();
    if (tid < 64) {
        float s = 0;
#pragma unroll
        for (int i = 0; i < 32; i++) s += sWz[tid * 32 + i];
        sSw[tid] = s;
    }
    __syncthreads();

    // ---- Phase 3: grouped conv ----
    int to2 = tid >> 4, th2 = tid & 15;   // [4 o][8 hw] per thread
    float zz[4][8];
#pragma unroll
    for (int j = 0; j < 4; j++) {
        float base = c0v * sSw[to2 * 4 + j];
#pragma unroll
        for (int k = 0; k < 8; k++) zz[j][k] = base;
    }
#pragma unroll
    for (int i = 0; i < 32; i++) {
        float4 xa = *(const float4*)&sBuf[i][th2 * 8];
        float4 xc = *(const float4*)&sBuf[i][th2 * 8 + 4];
#pragma unroll
        for (int j = 0; j < 4; j++) {
            float w = sWz[(to2 * 4 + j) * 32 + i];
            zz[j][0] += w * xa.x; zz[j][1] += w * xa.y;
            zz[j][2] += w * xa.z; zz[j][3] += w * xa.w;
            zz[j][4] += w * xc.x; zz[j][5] += w * xc.y;
            zz[j][6] += w * xc.z; zz[j][7] += w * xc.w;
        }
    }

    float s = 0, s2 = 0;
    float* zb = zout + ((size_t)b * C_ + g * OG_) * HW1 + hw0;
#pragma unroll
    for (int j = 0; j < 4; j++) {
        float4 v0 = make_float4(zz[j][0], zz[j][1], zz[j][2], zz[j][3]);
        float4 v1 = make_float4(zz[j][4], zz[j][5], zz[j][6], zz[j][7]);
        *(float4*)&zb[(size_t)(to2 * 4 + j) * HW1 + th2 * 8]     = v0;
        *(float4*)&zb[(size_t)(to2 * 4 + j) * HW1 + th2 * 8 + 4] = v1;
#pragma unroll
        for (int k = 0; k < 8; k++) { s += zz[j][k]; s2 += zz[j][k] * zz[j][k]; }
    }
    sred[tid] = s; sred[256 + tid] = s2;
    __syncthreads();
    for (int off = 128; off > 0; off >>= 1) {
        if (tid < off) {
            sred[tid] += sred[tid + off];
            sred[256 + tid] += sred[256 + tid + off];
        }
        __syncthreads();
    }
    if (tid == 0) {
        float* dst = zstat_part + (size_t)((b * G_ + g) * 32 + hwt) * 2;
        dst[0] = sred[0]; dst[1] = sred[256];
    }
}

// Reduce z stats -> mean, rsqrt(var+eps) per (b,g)
__global__ void k2b_gn(const float* __restrict__ zstat_part, float* __restrict__ gnstat)
{
    int t = threadIdx.x;
    if (t >= 128) return;
    float S = 0, S2 = 0;
    const float* p = zstat_part + (size_t)t * 32 * 2;
    for (int i = 0; i < 32; i++) { S += p[i * 2]; S2 += p[i * 2 + 1]; }
    const float N = 64.0f * 4096.0f;
    float mean = S / N;
    float var = S2 / N - mean * mean;
    var = var < 0.f ? 0.f : var;
    gnstat[t * 2] = mean;
    gnstat[t * 2 + 1] = rsqrtf(var + EPS_);
}

// ---------------------------------------------------------------------------
// K3: out = (z - mean)*rsig*gn_w + gn_b + input_high  (z read from d_out, in place)
// 8192 blocks * 256 threads * 4 float4 = 33,554,432 elements exactly.
// ---------------------------------------------------------------------------
__global__ __launch_bounds__(256)
void k3_final(float* __restrict__ out, const float* __restrict__ xhi,
              const float* __restrict__ gnstat, const float* __restrict__ gnw,
              const float* __restrict__ gnb)
{
#pragma unroll
    for (int k = 0; k < 4; k++) {
        size_t idx = (size_t)blockIdx.x * 1024 + (size_t)k * 256 + threadIdx.x; // f4 index
        size_t e = idx * 4;
        int ch = (int)((e >> 12) & 511);
        int b  = (int)(e >> 21);
        int gg = ch >> 6;
        const float* gs = gnstat + (size_t)(b * 8 + gg) * 2;
        float mean = gs[0];
        float w = gnw[ch] * gs[1];
        float bb = gnb[ch];
        float4 z = ((const float4*)out)[idx];
        float4 xv = ((const float4*)xhi)[idx];
        float4 r;
        r.x = (z.x - mean) * w + bb + xv.x;
        r.y = (z.y - mean) * w + bb + xv.y;
        r.z = (z.z - mean) * w + bb + xv.z;
        r.w = (z.w - mean) * w + bb + xv.w;
        ((float4*)out)[idx] = r;
    }
}

extern "C" void kernel_launch(void* const* d_in, const int* in_sizes, int n_in,
                              void* d_out, int out_size, void* d_ws, size_t ws_size,
                              hipStream_t stream) {
    (void)in_sizes; (void)n_in; (void)out_size; (void)ws_size;
    const float* xhi = (const float*)d_in[0];
    const float* xlo = (const float*)d_in[1];
    const float* Wt  = (const float*)d_in[2];
    const float* Wp  = (const float*)d_in[3];
    const float* Wg  = (const float*)d_in[4];
    const float* Wz  = (const float*)d_in[5];
    const float* gnw = (const float*)d_in[6];
    const float* gnb = (const float*)d_in[7];
    float* out = (float*)d_out;
    float* ws  = (float*)d_ws;

    float* att_part = ws;            // 16*8*8*3  = 3072 floats
    float* coef     = ws + 3072;     // 16*8*3    = 384
    float* zstat    = ws + 3456;     // 16*8*32*2 = 8192
    float* gnstat   = ws + 11648;    // 16*8*2    = 256

    // alpha_k^2 = (2*gamma)^k / k! * exp(-2*gamma), gamma = 1e-4
    double g2 = 2.0e-4;
    double ee = exp(-g2);
    float a0s = (float)ee;
    float a1s = (float)(g2 * ee);
    float a2s = (float)(g2 * g2 * 0.5 * ee);

    k1_att <<<dim3(1024), dim3(256), 0, stream>>>(xlo, Wp, Wg, att_part);
    k1b_coef<<<dim3(1),    dim3(128), 0, stream>>>(att_part, coef, a0s, a1s, a2s);
    k2_main <<<dim3(4096), dim3(256), 0, stream>>>(xhi, Wt, Wz, coef, out, zstat);
    k2b_gn  <<<dim3(1),    dim3(128), 0, stream>>>(zstat, gnstat);
    k3_final<<<dim3(8192), dim3(256), 0, stream>>>(out, xhi, gnstat, gnw, gnb);
}

// Round 3
// 382.746 us; speedup vs baseline: 1.1892x; 1.1892x over previous
//
#include <hip/hip_runtime.h>
#include <math.h>

typedef __attribute__((ext_vector_type(8))) short short8;
typedef __attribute__((ext_vector_type(8))) unsigned short u16x8;
typedef __attribute__((ext_vector_type(4))) unsigned short u16x4;
typedef __attribute__((ext_vector_type(2))) unsigned short u16x2;
typedef __attribute__((ext_vector_type(4))) float f32x4;

#define EPS_ 1e-5f

__device__ inline unsigned short cvt_bf16(float f) {
    union { float f; unsigned int u; } v; v.f = f;
    unsigned int u = v.u;
    return (unsigned short)((u + 0x7FFFu + ((u >> 16) & 1u)) >> 16);
}

__device__ inline f32x4 mfma16(u16x8 a, u16x8 b, f32x4 c) {
    return __builtin_amdgcn_mfma_f32_16x16x32_bf16((short8)a, (short8)b, c, 0, 0, 0);
}

// ---------------------------------------------------------------------------
// k0s: sxsum[b][c] = sum_hw xlo[b][c][:]   (exact fp32, feeds exact S0)
// grid 256 = (b:16, cgrp:16), 256 thr; thread = (c_local:32, seg:8)
// ---------------------------------------------------------------------------
__global__ __launch_bounds__(256)
void k0s(const float* __restrict__ xlo, float* __restrict__ sxsum)
{
    __shared__ float sred[256];
    int blk = blockIdx.x;
    int cgrp = blk & 15, b = blk >> 4;
    int tid = threadIdx.x;
    int cl = tid >> 3, seg = tid & 7;
    int c = cgrp * 32 + cl;
    const float* row = xlo + ((size_t)b * 512 + c) * 1024 + seg * 128;
    float s = 0.f;
#pragma unroll
    for (int i = 0; i < 32; i++) {
        float4 v = ((const float4*)row)[i];
        s += v.x + v.y + v.z + v.w;
    }
    sred[tid] = s;
    __syncthreads();
    if (seg == 0) {
        float t = 0.f;
#pragma unroll
        for (int e = 0; e < 8; e++) t += sred[cl * 8 + e];
        sxsum[(size_t)b * 512 + c] = t;
    }
}

// ---------------------------------------------------------------------------
// k1: MFMA p/g projections -> S1 = sum(p*g), S2 = sum(p^2*g) partials.
// grid 256 = (b:16, tile:16); block covers 256 planes x 64 hw, K=512 (chunks 32).
// Wave w owns planes [64w, 64w+64) = groups {2w, 2w+1}. LDS 36 KB.
// ---------------------------------------------------------------------------
__global__ __launch_bounds__(256)
void k1_att(const float* __restrict__ xlo, const float* __restrict__ Wp,
            const float* __restrict__ Wg, float* __restrict__ att_part)
{
    __shared__ unsigned short sWp[256 * 32];   // 16 KB [p][c]
    __shared__ unsigned short sWg[256 * 32];   // 16 KB
    __shared__ unsigned short sX1[64 * 32];    // 4 KB  [hw][c]

    int tid = threadIdx.x;
    int w = tid >> 6, lane = tid & 63;
    int l15 = lane & 15, l4 = lane >> 4;
    int beta = blockIdx.x;
    int tile = beta & 15, b = beta >> 4;
    int hw0 = tile * 64;

    const float* xg = xlo + (size_t)b * 512 * 1024 + hw0;

    f32x4 pacc[4][4] = {};
    f32x4 gacc[4][4] = {};

    int hq = tid & 15, cs = tid >> 4;   // hw-quad 0..15, c-pair 0..15

    for (int c0 = 0; c0 < 512; c0 += 32) {
        __syncthreads();
        // stage weight chunks [256][32], fp32 -> bf16
#pragma unroll
        for (int k = 0; k < 8; k++) {
            int idx = k * 256 + tid;
            int row = idx >> 3, cq = idx & 7;
            float4 vp = *(const float4*)&Wp[(size_t)row * 512 + c0 + cq * 4];
            float4 vg = *(const float4*)&Wg[(size_t)row * 512 + c0 + cq * 4];
            u16x4 op = { cvt_bf16(vp.x), cvt_bf16(vp.y), cvt_bf16(vp.z), cvt_bf16(vp.w) };
            u16x4 og = { cvt_bf16(vg.x), cvt_bf16(vg.y), cvt_bf16(vg.z), cvt_bf16(vg.w) };
            *(u16x4*)&sWp[row * 32 + cq * 4] = op;
            *(u16x4*)&sWg[row * 32 + cq * 4] = og;
        }
        // stage x transposed: [32c][64hw] fp32 -> sX1[hw][c] bf16
        {
            float4 v0 = *(const float4*)&xg[(size_t)(c0 + cs * 2 + 0) * 1024 + hq * 4];
            float4 v1 = *(const float4*)&xg[(size_t)(c0 + cs * 2 + 1) * 1024 + hq * 4];
#pragma unroll
            for (int j = 0; j < 4; j++) {
                u16x2 o = { cvt_bf16(((const float*)&v0)[j]), cvt_bf16(((const float*)&v1)[j]) };
                *(u16x2*)&sX1[(hq * 4 + j) * 32 + cs * 2] = o;
            }
        }
        __syncthreads();
        u16x8 bf[4];
#pragma unroll
        for (int ht = 0; ht < 4; ht++)
            bf[ht] = *(const u16x8*)&sX1[(ht * 16 + l15) * 32 + l4 * 8];
#pragma unroll
        for (int i = 0; i < 4; i++) {
            u16x8 ap = *(const u16x8*)&sWp[(w * 64 + i * 16 + l15) * 32 + l4 * 8];
            u16x8 ag = *(const u16x8*)&sWg[(w * 64 + i * 16 + l15) * 32 + l4 * 8];
#pragma unroll
            for (int ht = 0; ht < 4; ht++) {
                pacc[i][ht] = mfma16(ap, bf[ht], pacc[i][ht]);
                gacc[i][ht] = mfma16(ag, bf[ht], gacc[i][ht]);
            }
        }
    }

    float s1[2] = {0, 0}, s2[2] = {0, 0};
#pragma unroll
    for (int i = 0; i < 4; i++) {
        int u = i >> 1;
#pragma unroll
        for (int ht = 0; ht < 4; ht++) {
#pragma unroll
            for (int r = 0; r < 4; r++) {
                float pv = pacc[i][ht][r], gv = gacc[i][ht][r];
                s1[u] += pv * gv; s2[u] += pv * pv * gv;
            }
        }
    }
#pragma unroll
    for (int m = 1; m < 64; m <<= 1) {
#pragma unroll
        for (int u = 0; u < 2; u++) {
            s1[u] += __shfl_xor(s1[u], m);
            s2[u] += __shfl_xor(s2[u], m);
        }
    }
    if (lane == 0) {
#pragma unroll
        for (int u = 0; u < 2; u++) {
            float* dst = att_part + ((size_t)((b * 8 + 2 * w + u) * 16) + tile) * 2;
            dst[0] = s1[u]; dst[1] = s2[u];
        }
    }
}

// ---------------------------------------------------------------------------
// k1b: one wave per (b,g). Exact S0 = sum_c colsum(Wg)[c]*sxsum[b][c] (fp32);
// S1,S2 reduced from att_part. coef = alpha_k^2 * S_k.
// ---------------------------------------------------------------------------
__global__ __launch_bounds__(64)
void k1b_coef(const float* __restrict__ Wg, const float* __restrict__ sxsum,
              const float* __restrict__ att_part, float* __restrict__ coef,
              float a0s, float a1s, float a2s)
{
    int bg = blockIdx.x;
    int b = bg >> 3, g = bg & 7;
    int l = threadIdx.x;
    float s0 = 0.f;
    for (int cc = 0; cc < 512; cc += 64) {
        int c = cc + l;
        float cs = 0.f;
#pragma unroll
        for (int pp = 0; pp < 32; pp++) cs += Wg[(size_t)(g * 32 + pp) * 512 + c];
        s0 += cs * sxsum[(size_t)b * 512 + c];
    }
    float s1 = (l < 16) ? att_part[((size_t)bg * 16 + l) * 2 + 0] : 0.f;
    float s2 = (l < 16) ? att_part[((size_t)bg * 16 + l) * 2 + 1] : 0.f;
#pragma unroll
    for (int m = 1; m < 64; m <<= 1) {
        s0 += __shfl_xor(s0, m);
        s1 += __shfl_xor(s1, m);
        s2 += __shfl_xor(s2, m);
    }
    if (l == 0) {
        coef[bg * 3 + 0] = a0s * s0;
        coef[bg * 3 + 1] = a1s * s1;
        coef[bg * 3 + 2] = a2s * s2;
    }
}

// ---------------------------------------------------------------------------
// k2: MFMA t-GEMM -> poly -> (2-pass) MFMA grouped conv -> z fp32 + GN partials
// grid 512 = (b:16, hwt:32); 256 planes x 128 hw, K=512 (chunks 64). LDS 50 KB:
// sBig 32KB doubles as Wt-stage [256][64] then xx [128 hw][128 p_local].
// ---------------------------------------------------------------------------
__global__ __launch_bounds__(256)
void k2_main(const float* __restrict__ xhi, const float* __restrict__ Wt,
             const float* __restrict__ Wz, const float* __restrict__ coef,
             float* __restrict__ zout, float* __restrict__ zstat)
{
    __shared__ unsigned short sBig[256 * 64];   // 32 KB
    __shared__ unsigned short sX2[128 * 64];    // 16 KB [hw][c]
    __shared__ float sR[512];                   // 2 KB

    int tid = threadIdx.x;
    int w = tid >> 6, lane = tid & 63;
    int l15 = lane & 15, l4 = lane >> 4;
    int beta = blockIdx.x;
    int hwt = beta & 31, b = beta >> 5;
    int hw0 = hwt * 128;

    // R[ch] = rowsum(Wz) in fp32
#pragma unroll
    for (int e = 0; e < 2; e++) {
        int ch = tid * 2 + e;
        const float* wr = Wz + (size_t)ch * 32;
        float s = 0.f;
#pragma unroll
        for (int q = 0; q < 8; q++) {
            float4 v = ((const float4*)wr)[q];
            s += v.x + v.y + v.z + v.w;
        }
        sR[ch] = s;
    }

    float c1v[2], c2v[2];
#pragma unroll
    for (int u = 0; u < 2; u++) {
        const float* cf = coef + (size_t)(b * 8 + 2 * w + u) * 3;
        c1v[u] = cf[1]; c2v[u] = cf[2];
    }

    const float* xg = xhi + (size_t)b * 512 * 4096 + hw0;
    f32x4 acc[4][8] = {};
    int hq = tid & 31, cq8 = tid >> 5;

    for (int c0 = 0; c0 < 512; c0 += 64) {
        __syncthreads();
        // stage Wt chunk [256][64] fp32 -> bf16
#pragma unroll
        for (int k = 0; k < 16; k++) {
            int idx = k * 256 + tid;
            int row = idx >> 4, cq = idx & 15;
            float4 v = *(const float4*)&Wt[(size_t)row * 512 + c0 + cq * 4];
            u16x4 o = { cvt_bf16(v.x), cvt_bf16(v.y), cvt_bf16(v.z), cvt_bf16(v.w) };
            *(u16x4*)&sBig[row * 64 + cq * 4] = o;
        }
        // stage x transposed: [64c][128hw] fp32 -> sX2[hw][c] bf16
#pragma unroll
        for (int s = 0; s < 2; s++) {
            int cq = cq8 + 8 * s;
            float4 v0 = *(const float4*)&xg[(size_t)(c0 + cq * 4 + 0) * 4096 + hq * 4];
            float4 v1 = *(const float4*)&xg[(size_t)(c0 + cq * 4 + 1) * 4096 + hq * 4];
            float4 v2 = *(const float4*)&xg[(size_t)(c0 + cq * 4 + 2) * 4096 + hq * 4];
            float4 v3 = *(const float4*)&xg[(size_t)(c0 + cq * 4 + 3) * 4096 + hq * 4];
#pragma unroll
            for (int j = 0; j < 4; j++) {
                u16x4 o = { cvt_bf16(((const float*)&v0)[j]), cvt_bf16(((const float*)&v1)[j]),
                            cvt_bf16(((const float*)&v2)[j]), cvt_bf16(((const float*)&v3)[j]) };
                *(u16x4*)&sX2[(hq * 4 + j) * 64 + cq * 4] = o;
            }
        }
        __syncthreads();
#pragma unroll
        for (int kk = 0; kk < 2; kk++) {
            u16x8 bf[8];
#pragma unroll
            for (int ht = 0; ht < 8; ht++)
                bf[ht] = *(const u16x8*)&sX2[(ht * 16 + l15) * 64 + kk * 32 + l4 * 8];
#pragma unroll
            for (int i = 0; i < 4; i++) {
                u16x8 af = *(const u16x8*)&sBig[(w * 64 + i * 16 + l15) * 64 + kk * 32 + l4 * 8];
#pragma unroll
                for (int ht = 0; ht < 8; ht++)
                    acc[i][ht] = mfma16(af, bf[ht], acc[i][ht]);
            }
        }
    }

    // poly in-place: xx = c1*t + c2*t^2
#pragma unroll
    for (int i = 0; i < 4; i++) {
        int u = i >> 1;
#pragma unroll
        for (int ht = 0; ht < 8; ht++) {
            f32x4 t = acc[i][ht];
            acc[i][ht] = c1v[u] * t + c2v[u] * t * t;
        }
    }

    // two conv passes over plane halves; sBig reused as xx[128 hw][128 p_local]
    for (int pass = 0; pass < 2; pass++) {
        __syncthreads();
        if ((w >> 1) == pass) {
            int pbase = (w & 1) * 64;
#pragma unroll
            for (int i = 0; i < 4; i++) {
#pragma unroll
                for (int ht = 0; ht < 8; ht++) {
                    f32x4 xv = acc[i][ht];
                    u16x4 o = { cvt_bf16(xv[0]), cvt_bf16(xv[1]), cvt_bf16(xv[2]), cvt_bf16(xv[3]) };
                    *(u16x4*)&sBig[(ht * 16 + l15) * 128 + pbase + i * 16 + l4 * 4] = o;
                }
            }
        }
        __syncthreads();
        int g = pass * 4 + w;
        int ch_base = g * 64;
        float c0p = coef[(size_t)(b * 8 + g) * 3];
        u16x8 wzf[4];
#pragma unroll
        for (int ot = 0; ot < 4; ot++) {
            const float* wr = Wz + (size_t)(ch_base + ot * 16 + l15) * 32 + l4 * 8;
            float4 v0 = ((const float4*)wr)[0];
            float4 v1 = ((const float4*)wr)[1];
            u16x8 o = { cvt_bf16(v0.x), cvt_bf16(v0.y), cvt_bf16(v0.z), cvt_bf16(v0.w),
                        cvt_bf16(v1.x), cvt_bf16(v1.y), cvt_bf16(v1.z), cvt_bf16(v1.w) };
            wzf[ot] = o;
        }
        float s = 0.f, s2 = 0.f;
        f32x4 zero4 = {0.f, 0.f, 0.f, 0.f};
#pragma unroll
        for (int ht = 0; ht < 8; ht++) {
            u16x8 bfr = *(const u16x8*)&sBig[(ht * 16 + l15) * 128 + w * 32 + l4 * 8];
#pragma unroll
            for (int ot = 0; ot < 4; ot++) {
                f32x4 z = mfma16(wzf[ot], bfr, zero4);
                f32x4 rv = *(const f32x4*)&sR[ch_base + ot * 16 + l4 * 4];
                z = z + c0p * rv;
                float* zp = zout + ((size_t)(b * 512 + ch_base + ot * 16 + l4 * 4)) * 4096
                          + hw0 + ht * 16 + l15;
#pragma unroll
                for (int r = 0; r < 4; r++) {
                    zp[(size_t)r * 4096] = z[r];
                    s += z[r]; s2 += z[r] * z[r];
                }
            }
        }
#pragma unroll
        for (int m = 1; m < 64; m <<= 1) {
            s  += __shfl_xor(s, m);
            s2 += __shfl_xor(s2, m);
        }
        if (lane == 0) {
            float* dst = zstat + ((size_t)(b * 8 + g) * 32 + hwt) * 2;
            dst[0] = s; dst[1] = s2;
        }
    }
}

__global__ void k2b_gn(const float* __restrict__ zstat, float* __restrict__ gnstat)
{
    int t = threadIdx.x;
    if (t >= 128) return;
    float S = 0.f, S2 = 0.f;
    const float* p = zstat + (size_t)t * 32 * 2;
    for (int i = 0; i < 32; i++) { S += p[i * 2]; S2 += p[i * 2 + 1]; }
    const float N = 64.0f * 4096.0f;
    float mean = S / N;
    float var = S2 / N - mean * mean;
    var = var < 0.f ? 0.f : var;
    gnstat[t * 2] = mean;
    gnstat[t * 2 + 1] = rsqrtf(var + EPS_);
}

// ---------------------------------------------------------------------------
// k3: out = (z - mean)*rsig*gn_w + gn_b + input_high  (in place on d_out)
// ---------------------------------------------------------------------------
__global__ __launch_bounds__(256)
void k3_final(float* __restrict__ out, const float* __restrict__ xhi,
              const float* __restrict__ gnstat, const float* __restrict__ gnw,
              const float* __restrict__ gnb)
{
#pragma unroll
    for (int k = 0; k < 4; k++) {
        size_t idx = (size_t)blockIdx.x * 1024 + (size_t)k * 256 + threadIdx.x; // f4 index
        size_t e = idx * 4;
        int ch = (int)((e >> 12) & 511);
        int b  = (int)(e >> 21);
        int gg = ch >> 6;
        const float* gs = gnstat + (size_t)(b * 8 + gg) * 2;
        float mean = gs[0];
        float w = gnw[ch] * gs[1];
        float bb = gnb[ch];
        float4 z = ((const float4*)out)[idx];
        float4 xv = ((const float4*)xhi)[idx];
        float4 r;
        r.x = (z.x - mean) * w + bb + xv.x;
        r.y = (z.y - mean) * w + bb + xv.y;
        r.z = (z.z - mean) * w + bb + xv.z;
        r.w = (z.w - mean) * w + bb + xv.w;
        ((float4*)out)[idx] = r;
    }
}

extern "C" void kernel_launch(void* const* d_in, const int* in_sizes, int n_in,
                              void* d_out, int out_size, void* d_ws, size_t ws_size,
                              hipStream_t stream) {
    (void)in_sizes; (void)n_in; (void)out_size; (void)ws_size;
    const float* xhi = (const float*)d_in[0];
    const float* xlo = (const float*)d_in[1];
    const float* Wt  = (const float*)d_in[2];
    const float* Wp  = (const float*)d_in[3];
    const float* Wg  = (const float*)d_in[4];
    const float* Wz  = (const float*)d_in[5];
    const float* gnw = (const float*)d_in[6];
    const float* gnb = (const float*)d_in[7];
    float* out = (float*)d_out;
    float* ws  = (float*)d_ws;

    float* sxsum    = ws;              // 16*512       = 8192 floats
    float* att_part = ws + 8192;       // 128*16*2     = 4096
    float* coef     = ws + 12288;      // 128*3        = 384
    float* zstat    = ws + 12672;      // 128*32*2     = 8192
    float* gnstat   = ws + 20864;      // 128*2        = 256   (total ~84.5 KB)

    // alpha_k^2 = (2*gamma)^k / k! * exp(-2*gamma), gamma = 1e-4
    double g2 = 2.0e-4;
    double ee = exp(-g2);
    float a0s = (float)ee;
    float a1s = (float)(g2 * ee);
    float a2s = (float)(g2 * g2 * 0.5 * ee);

    k0s     <<<dim3(256),  dim3(256), 0, stream>>>(xlo, sxsum);
    k1_att  <<<dim3(256),  dim3(256), 0, stream>>>(xlo, Wp, Wg, att_part);
    k1b_coef<<<dim3(128),  dim3(64),  0, stream>>>(Wg, sxsum, att_part, coef, a0s, a1s, a2s);
    k2_main <<<dim3(512),  dim3(256), 0, stream>>>(xhi, Wt, Wz, coef, out, zstat);
    k2b_gn  <<<dim3(1),    dim3(128), 0, stream>>>(zstat, gnstat);
    k3_final<<<dim3(8192), dim3(256), 0, stream>>>(out, xhi, gnstat, gnw, gnb);
}

// Round 5
// 374.608 us; speedup vs baseline: 1.2150x; 1.0217x over previous
//
#include <hip/hip_runtime.h>
#include <math.h>

typedef __attribute__((ext_vector_type(8))) short short8;
typedef __attribute__((ext_vector_type(8))) unsigned short u16x8;
typedef __attribute__((ext_vector_type(4))) unsigned short u16x4;
typedef __attribute__((ext_vector_type(2))) unsigned short u16x2;
typedef __attribute__((ext_vector_type(4))) float f32x4;

#define EPS_ 1e-5f

__device__ inline unsigned short cvt_bf16(float f) {
    union { float f; unsigned int u; } v; v.f = f;
    unsigned int u = v.u;
    return (unsigned short)((u + 0x7FFFu + ((u >> 16) & 1u)) >> 16);
}

__device__ inline f32x4 mfma16(u16x8 a, u16x8 b, f32x4 c) {
    return __builtin_amdgcn_mfma_f32_16x16x32_bf16((short8)a, (short8)b, c, 0, 0, 0);
}

// ---------------------------------------------------------------------------
// k0s: sxsum[b][c] = sum_hw xlo[b][c][:]   (exact fp32, feeds exact S0)
// ---------------------------------------------------------------------------
__global__ __launch_bounds__(256)
void k0s(const float* __restrict__ xlo, float* __restrict__ sxsum)
{
    __shared__ float sred[256];
    int blk = blockIdx.x;
    int cgrp = blk & 15, b = blk >> 4;
    int tid = threadIdx.x;
    int cl = tid >> 3, seg = tid & 7;
    int c = cgrp * 32 + cl;
    const float* row = xlo + ((size_t)b * 512 + c) * 1024 + seg * 128;
    float s = 0.f;
#pragma unroll
    for (int i = 0; i < 32; i++) {
        float4 v = ((const float4*)row)[i];
        s += v.x + v.y + v.z + v.w;
    }
    sred[tid] = s;
    __syncthreads();
    if (seg == 0) {
        float t = 0.f;
#pragma unroll
        for (int e = 0; e < 8; e++) t += sred[cl * 8 + e];
        sxsum[(size_t)b * 512 + c] = t;
    }
}

// ---------------------------------------------------------------------------
// k1: MFMA p/g projections -> S1,S2 partials (frozen from round 3 / passing).
// grid 256 = (b:16, tile:16); 256 planes x 64 hw, K=512 chunks of 32.
// ---------------------------------------------------------------------------
__global__ __launch_bounds__(256)
void k1_att(const float* __restrict__ xlo, const float* __restrict__ Wp,
            const float* __restrict__ Wg, float* __restrict__ att_part)
{
    __shared__ unsigned short sWp[256 * 32];   // 16 KB [p][c]
    __shared__ unsigned short sWg[256 * 32];   // 16 KB
    __shared__ unsigned short sX1[64 * 32];    // 4 KB  [hw][c]

    int tid = threadIdx.x;
    int w = tid >> 6, lane = tid & 63;
    int l15 = lane & 15, l4 = lane >> 4;
    int beta = blockIdx.x;
    int tile = beta & 15, b = beta >> 4;
    int hw0 = tile * 64;

    const float* xg = xlo + (size_t)b * 512 * 1024 + hw0;

    f32x4 pacc[4][4] = {};
    f32x4 gacc[4][4] = {};

    int hq = tid & 15, cs = tid >> 4;

    for (int c0 = 0; c0 < 512; c0 += 32) {
        __syncthreads();
#pragma unroll
        for (int k = 0; k < 8; k++) {
            int idx = k * 256 + tid;
            int row = idx >> 3, cq = idx & 7;
            float4 vp = *(const float4*)&Wp[(size_t)row * 512 + c0 + cq * 4];
            float4 vg = *(const float4*)&Wg[(size_t)row * 512 + c0 + cq * 4];
            u16x4 op = { cvt_bf16(vp.x), cvt_bf16(vp.y), cvt_bf16(vp.z), cvt_bf16(vp.w) };
            u16x4 og = { cvt_bf16(vg.x), cvt_bf16(vg.y), cvt_bf16(vg.z), cvt_bf16(vg.w) };
            *(u16x4*)&sWp[row * 32 + cq * 4] = op;
            *(u16x4*)&sWg[row * 32 + cq * 4] = og;
        }
        {
            float4 v0 = *(const float4*)&xg[(size_t)(c0 + cs * 2 + 0) * 1024 + hq * 4];
            float4 v1 = *(const float4*)&xg[(size_t)(c0 + cs * 2 + 1) * 1024 + hq * 4];
#pragma unroll
            for (int j = 0; j < 4; j++) {
                u16x2 o = { cvt_bf16(((const float*)&v0)[j]), cvt_bf16(((const float*)&v1)[j]) };
                *(u16x2*)&sX1[(hq * 4 + j) * 32 + cs * 2] = o;
            }
        }
        __syncthreads();
        u16x8 bf[4];
#pragma unroll
        for (int ht = 0; ht < 4; ht++)
            bf[ht] = *(const u16x8*)&sX1[(ht * 16 + l15) * 32 + l4 * 8];
#pragma unroll
        for (int i = 0; i < 4; i++) {
            u16x8 ap = *(const u16x8*)&sWp[(w * 64 + i * 16 + l15) * 32 + l4 * 8];
            u16x8 ag = *(const u16x8*)&sWg[(w * 64 + i * 16 + l15) * 32 + l4 * 8];
#pragma unroll
            for (int ht = 0; ht < 4; ht++) {
                pacc[i][ht] = mfma16(ap, bf[ht], pacc[i][ht]);
                gacc[i][ht] = mfma16(ag, bf[ht], gacc[i][ht]);
            }
        }
    }

    float s1[2] = {0, 0}, s2[2] = {0, 0};
#pragma unroll
    for (int i = 0; i < 4; i++) {
        int u = i >> 1;
#pragma unroll
        for (int ht = 0; ht < 4; ht++) {
#pragma unroll
            for (int r = 0; r < 4; r++) {
                float pv = pacc[i][ht][r], gv = gacc[i][ht][r];
                s1[u] += pv * gv; s2[u] += pv * pv * gv;
            }
        }
    }
#pragma unroll
    for (int m = 1; m < 64; m <<= 1) {
#pragma unroll
        for (int u = 0; u < 2; u++) {
            s1[u] += __shfl_xor(s1[u], m);
            s2[u] += __shfl_xor(s2[u], m);
        }
    }
    if (lane == 0) {
#pragma unroll
        for (int u = 0; u < 2; u++) {
            float* dst = att_part + ((size_t)((b * 8 + 2 * w + u) * 16) + tile) * 2;
            dst[0] = s1[u]; dst[1] = s2[u];
        }
    }
}

// ---------------------------------------------------------------------------
// k1b: one wave per (b,g). Exact fp32 S0 via colsum(Wg)·hwsum(xlo).
// ---------------------------------------------------------------------------
__global__ __launch_bounds__(64)
void k1b_coef(const float* __restrict__ Wg, const float* __restrict__ sxsum,
              const float* __restrict__ att_part, float* __restrict__ coef,
              float a0s, float a1s, float a2s)
{
    int bg = blockIdx.x;
    int b = bg >> 3, g = bg & 7;
    int l = threadIdx.x;
    float s0 = 0.f;
    for (int cc = 0; cc < 512; cc += 64) {
        int c = cc + l;
        float cs = 0.f;
#pragma unroll
        for (int pp = 0; pp < 32; pp++) cs += Wg[(size_t)(g * 32 + pp) * 512 + c];
        s0 += cs * sxsum[(size_t)b * 512 + c];
    }
    float s1 = (l < 16) ? att_part[((size_t)bg * 16 + l) * 2 + 0] : 0.f;
    float s2 = (l < 16) ? att_part[((size_t)bg * 16 + l) * 2 + 1] : 0.f;
#pragma unroll
    for (int m = 1; m < 64; m <<= 1) {
        s0 += __shfl_xor(s0, m);
        s1 += __shfl_xor(s1, m);
        s2 += __shfl_xor(s2, m);
    }
    if (l == 0) {
        coef[bg * 3 + 0] = a0s * s0;
        coef[bg * 3 + 1] = a1s * s1;
        coef[bg * 3 + 2] = a2s * s2;
    }
}

// ---------------------------------------------------------------------------
// k2: t-GEMM (MFMA) -> poly -> grouped conv (MFMA) -> z fp32 + GN partials.
// grid 1024 = (b:16, hwt:64). 256 planes x 64 hw, K=512 (chunks 64).
// LDS 42 KB: sMain 32KB (Wt chunk [256][64] swz, then xx [64hw][256p] swz),
// sX 8KB ([64hw][64c] swz), sR 2KB. All LDS granule-XOR-swizzled (T2).
// Wave w: t-planes [64w,64w+64); conv ch [128w,128w+128) = groups {2w,2w+1}.
// Stats accumulated via fp32 atomicAdd into zstat[128][2] (zeroed on stream).
// ---------------------------------------------------------------------------
__global__ __launch_bounds__(256)
void k2_main(const float* __restrict__ xhi, const float* __restrict__ Wt,
             const float* __restrict__ Wz, const float* __restrict__ coef,
             float* __restrict__ zout, float* __restrict__ zstat)
{
    __shared__ unsigned short sMain[16384];  // 32 KB
    __shared__ unsigned short sX[4096];      // 8 KB
    __shared__ float sR[512];                // 2 KB

    int tid = threadIdx.x;
    int w = tid >> 6, lane = tid & 63;
    int l15 = lane & 15, l4 = lane >> 4;
    int hwt = blockIdx.x & 63, b = blockIdx.x >> 6;
    int hw0 = hwt * 64;
    int xrow = tid & 63, chalf = tid >> 6;

    // R[ch] = rowsum(Wz) fp32 (L2-resident re-read)
#pragma unroll
    for (int e = 0; e < 2; e++) {
        int ch = tid * 2 + e;
        const float* wr = Wz + (size_t)ch * 32;
        float s = 0.f;
#pragma unroll
        for (int q = 0; q < 8; q++) {
            float4 v = ((const float4*)wr)[q];
            s += v.x + v.y + v.z + v.w;
        }
        sR[ch] = s;
    }

    float c0v[2], c1v[2], c2v[2];
#pragma unroll
    for (int u = 0; u < 2; u++) {
        const float* cf = coef + (size_t)(b * 8 + 2 * w + u) * 3;
        c0v[u] = cf[0]; c1v[u] = cf[1]; c2v[u] = cf[2];
    }

    f32x4 acc[4][4] = {};

    for (int kc = 0; kc < 8; kc++) {
        int c0 = kc * 64;
        __syncthreads();
        // ---- stage Wt chunk [256 rows][64 c] -> sMain, granule slot ^= row&7
#pragma unroll
        for (int k = 0; k < 8; k++) {
            int idx = k * 256 + tid;
            int row = idx >> 3, s = idx & 7;
            const float* sp = Wt + (size_t)row * 512 + c0 + s * 8;
            float4 v0 = ((const float4*)sp)[0];
            float4 v1 = ((const float4*)sp)[1];
            u16x8 o = { cvt_bf16(v0.x), cvt_bf16(v0.y), cvt_bf16(v0.z), cvt_bf16(v0.w),
                        cvt_bf16(v1.x), cvt_bf16(v1.y), cvt_bf16(v1.z), cvt_bf16(v1.w) };
            *(u16x8*)&sMain[row * 64 + ((s ^ (row & 7)) << 3)] = o;
        }
        // ---- stage X: [64c][64hw] -> sX[hw][c] bf16, swizzled, conflict-free
        {
            const float* xcol = xhi + ((size_t)b * 512 + c0 + chalf * 16) * 4096 + hw0 + xrow;
            float v[16];
#pragma unroll
            for (int cc = 0; cc < 16; cc++) v[cc] = xcol[(size_t)cc * 4096];
#pragma unroll
            for (int h = 0; h < 2; h++) {
                u16x8 o = { cvt_bf16(v[h*8+0]), cvt_bf16(v[h*8+1]), cvt_bf16(v[h*8+2]),
                            cvt_bf16(v[h*8+3]), cvt_bf16(v[h*8+4]), cvt_bf16(v[h*8+5]),
                            cvt_bf16(v[h*8+6]), cvt_bf16(v[h*8+7]) };
                int phys = (chalf * 2 + h) ^ (xrow & 7);
                *(u16x8*)&sX[xrow * 64 + phys * 8] = o;
            }
        }
        __syncthreads();
#pragma unroll
        for (int kk = 0; kk < 2; kk++) {
            u16x8 bf[4];
#pragma unroll
            for (int ht = 0; ht < 4; ht++) {
                int row = ht * 16 + l15;
                bf[ht] = *(const u16x8*)&sX[row * 64 + (((kk * 4 + l4) ^ (row & 7)) << 3)];
            }
#pragma unroll
            for (int i = 0; i < 4; i++) {
                int row = w * 64 + i * 16 + l15;
                u16x8 af = *(const u16x8*)&sMain[row * 64 + (((kk * 4 + l4) ^ (row & 7)) << 3)];
#pragma unroll
                for (int ht = 0; ht < 4; ht++)
                    acc[i][ht] = mfma16(af, bf[ht], acc[i][ht]);
            }
        }
    }

    // poly in registers: xx = c1*t + c2*t^2
#pragma unroll
    for (int i = 0; i < 4; i++) {
        int u = i >> 1;
#pragma unroll
        for (int ht = 0; ht < 4; ht++) {
            f32x4 t = acc[i][ht];
            acc[i][ht] = c1v[u] * t + c2v[u] * t * t;
        }
    }
    __syncthreads();   // all A/B reads done -> reuse sMain as xx

    // xx -> sMain as [64 hw][256 p] bf16, wave-local granule swizzle
#pragma unroll
    for (int i = 0; i < 4; i++) {
#pragma unroll
        for (int ht = 0; ht < 4; ht++) {
            int row = ht * 16 + l15;
            f32x4 xv = acc[i][ht];
            u16x4 o = { cvt_bf16(xv[0]), cvt_bf16(xv[1]), cvt_bf16(xv[2]), cvt_bf16(xv[3]) };
            int phys = w * 8 + ((i * 2 + (l4 >> 1)) ^ (row & 7));
            *(u16x4*)&sMain[row * 256 + phys * 8 + (l4 & 1) * 4] = o;
        }
    }
    __syncthreads();

    // grouped conv: z = Wz@xx + c0*R  (wave w: channels [128w, 128w+128))
    u16x8 wzf[8];
#pragma unroll
    for (int ot = 0; ot < 8; ot++) {
        const float* wr = Wz + (size_t)(w * 128 + ot * 16 + l15) * 32 + l4 * 8;
        float4 v0 = ((const float4*)wr)[0];
        float4 v1 = ((const float4*)wr)[1];
        u16x8 o = { cvt_bf16(v0.x), cvt_bf16(v0.y), cvt_bf16(v0.z), cvt_bf16(v0.w),
                    cvt_bf16(v1.x), cvt_bf16(v1.y), cvt_bf16(v1.z), cvt_bf16(v1.w) };
        wzf[ot] = o;
    }

    float s[2] = {0, 0}, s2a[2] = {0, 0};
    f32x4 zero4 = {0.f, 0.f, 0.f, 0.f};
#pragma unroll
    for (int ht = 0; ht < 4; ht++) {
        int row = ht * 16 + l15;
        u16x8 bfr[2];
#pragma unroll
        for (int u = 0; u < 2; u++) {
            int phys = w * 8 + ((u * 4 + l4) ^ (row & 7));
            bfr[u] = *(const u16x8*)&sMain[row * 256 + phys * 8];
        }
#pragma unroll
        for (int ot = 0; ot < 8; ot++) {
            int u = ot >> 2;
            f32x4 z = mfma16(wzf[ot], bfr[u], zero4);
            f32x4 rv = *(const f32x4*)&sR[w * 128 + ot * 16 + l4 * 4];
            z = z + c0v[u] * rv;
            float* zp = zout + ((size_t)(b * 512 + w * 128 + ot * 16 + l4 * 4)) * 4096
                      + hw0 + ht * 16 + l15;
#pragma unroll
            for (int r = 0; r < 4; r++) {
                zp[(size_t)r * 4096] = z[r];
                s[u] += z[r]; s2a[u] += z[r] * z[r];
            }
        }
    }
#pragma unroll
    for (int m = 1; m < 64; m <<= 1) {
#pragma unroll
        for (int u = 0; u < 2; u++) {
            s[u]   += __shfl_xor(s[u], m);
            s2a[u] += __shfl_xor(s2a[u], m);
        }
    }
    if (lane == 0) {
#pragma unroll
        for (int u = 0; u < 2; u++) {
            atomicAdd(&zstat[(size_t)(b * 8 + 2 * w + u) * 2 + 0], s[u]);
            atomicAdd(&zstat[(size_t)(b * 8 + 2 * w + u) * 2 + 1], s2a[u]);
        }
    }
}

__global__ void k2b_gn(const float* __restrict__ zstat, float* __restrict__ gnstat)
{
    int t = threadIdx.x;
    if (t >= 128) return;
    float S = zstat[t * 2], S2 = zstat[t * 2 + 1];
    const float N = 64.0f * 4096.0f;
    float mean = S / N;
    float var = S2 / N - mean * mean;
    var = var < 0.f ? 0.f : var;
    gnstat[t * 2] = mean;
    gnstat[t * 2 + 1] = rsqrtf(var + EPS_);
}

// ---------------------------------------------------------------------------
// k3: out = (z - mean)*rsig*gn_w + gn_b + input_high  (in place on d_out)
// ---------------------------------------------------------------------------
__global__ __launch_bounds__(256)
void k3_final(float* __restrict__ out, const float* __restrict__ xhi,
              const float* __restrict__ gnstat, const float* __restrict__ gnw,
              const float* __restrict__ gnb)
{
#pragma unroll
    for (int k = 0; k < 4; k++) {
        size_t idx = (size_t)blockIdx.x * 1024 + (size_t)k * 256 + threadIdx.x; // f4 index
        size_t e = idx * 4;
        int ch = (int)((e >> 12) & 511);
        int b  = (int)(e >> 21);
        int gg = ch >> 6;
        const float* gs = gnstat + (size_t)(b * 8 + gg) * 2;
        float mean = gs[0];
        float w = gnw[ch] * gs[1];
        float bb = gnb[ch];
        float4 z = ((const float4*)out)[idx];
        float4 xv = ((const float4*)xhi)[idx];
        float4 r;
        r.x = (z.x - mean) * w + bb + xv.x;
        r.y = (z.y - mean) * w + bb + xv.y;
        r.z = (z.z - mean) * w + bb + xv.z;
        r.w = (z.w - mean) * w + bb + xv.w;
        ((float4*)out)[idx] = r;
    }
}

extern "C" void kernel_launch(void* const* d_in, const int* in_sizes, int n_in,
                              void* d_out, int out_size, void* d_ws, size_t ws_size,
                              hipStream_t stream) {
    (void)in_sizes; (void)n_in; (void)out_size; (void)ws_size;
    const float* xhi = (const float*)d_in[0];
    const float* xlo = (const float*)d_in[1];
    const float* Wt  = (const float*)d_in[2];
    const float* Wp  = (const float*)d_in[3];
    const float* Wg  = (const float*)d_in[4];
    const float* Wz  = (const float*)d_in[5];
    const float* gnw = (const float*)d_in[6];
    const float* gnb = (const float*)d_in[7];
    float* out = (float*)d_out;
    float* ws  = (float*)d_ws;

    float* sxsum    = ws;              // 8192 floats
    float* att_part = ws + 8192;       // 4096
    float* coef     = ws + 12288;      // 384
    float* zstat    = ws + 12672;      // 256 (128 x {S, S2})
    float* gnstat   = ws + 12928;      // 256   -> total 13184 f = 51.5 KB

    // alpha_k^2 = (2*gamma)^k / k! * exp(-2*gamma), gamma = 1e-4
    double g2 = 2.0e-4;
    double ee = exp(-g2);
    float a0s = (float)ee;
    float a1s = (float)(g2 * ee);
    float a2s = (float)(g2 * g2 * 0.5 * ee);

    k0s     <<<dim3(256),  dim3(256), 0, stream>>>(xlo, sxsum);
    k1_att  <<<dim3(256),  dim3(256), 0, stream>>>(xlo, Wp, Wg, att_part);
    k1b_coef<<<dim3(128),  dim3(64),  0, stream>>>(Wg, sxsum, att_part, coef, a0s, a1s, a2s);
    hipMemsetAsync(zstat, 0, 256 * sizeof(float), stream);
    k2_main <<<dim3(1024), dim3(256), 0, stream>>>(xhi, Wt, Wz, coef, out, zstat);
    k2b_gn  <<<dim3(1),    dim3(128), 0, stream>>>(zstat, gnstat);
    k3_final<<<dim3(8192), dim3(256), 0, stream>>>(out, xhi, gnstat, gnw, gnb);
}

// Round 6
// 266.896 us; speedup vs baseline: 1.7054x; 1.4036x over previous
//
#include <hip/hip_runtime.h>
#include <math.h>

typedef __attribute__((ext_vector_type(8))) short short8;
typedef __attribute__((ext_vector_type(8))) unsigned short u16x8;
typedef __attribute__((ext_vector_type(4))) unsigned short u16x4;
typedef __attribute__((ext_vector_type(4))) float f32x4;

#define EPS_ 1e-5f

__device__ inline unsigned short cvt_bf16(float f) {
    union { float f; unsigned int u; } v; v.f = f;
    unsigned int u = v.u;
    return (unsigned short)((u + 0x7FFFu + ((u >> 16) & 1u)) >> 16);
}

__device__ inline f32x4 mfma16(u16x8 a, u16x8 b, f32x4 c) {
    return __builtin_amdgcn_mfma_f32_16x16x32_bf16((short8)a, (short8)b, c, 0, 0, 0);
}

// ---------------------------------------------------------------------------
// k0s: sxsum[b][c] = sum_hw xlo[b][c][:]   (exact fp32, feeds exact S0)
// ---------------------------------------------------------------------------
__global__ __launch_bounds__(256)
void k0s(const float* __restrict__ xlo, float* __restrict__ sxsum)
{
    __shared__ float sred[256];
    int blk = blockIdx.x;
    int cgrp = blk & 15, b = blk >> 4;
    int tid = threadIdx.x;
    int cl = tid >> 3, seg = tid & 7;
    int c = cgrp * 32 + cl;
    const float* row = xlo + ((size_t)b * 512 + c) * 1024 + seg * 128;
    float s = 0.f;
#pragma unroll
    for (int i = 0; i < 32; i++) {
        float4 v = ((const float4*)row)[i];
        s += v.x + v.y + v.z + v.w;
    }
    sred[tid] = s;
    __syncthreads();
    if (seg == 0) {
        float t = 0.f;
#pragma unroll
        for (int e = 0; e < 8; e++) t += sred[cl * 8 + e];
        sxsum[(size_t)b * 512 + c] = t;
    }
}

// ---------------------------------------------------------------------------
// k1: MFMA p/g projections -> S1,S2 partials.
// grid 1024 = (b:16, mh:2, tile:32); block = 128 planes x 32 hw, K=512 (8x64).
// Wave w owns one group g = mh*4+w (local planes [32w, 32w+32)).
// LDS 36 KB (4 blocks/CU); X tile register-prefetched across chunks.
// ---------------------------------------------------------------------------
__global__ __launch_bounds__(256, 4)
void k1_att(const float* __restrict__ xlo, const float* __restrict__ Wp,
            const float* __restrict__ Wg, float* __restrict__ att_part)
{
    __shared__ unsigned short sWp[8192];   // 16 KB [128 rows][64 c] swizzled
    __shared__ unsigned short sWg[8192];   // 16 KB
    __shared__ unsigned short sX1[2048];   // 4 KB  [32 hw][64 c] swizzled

    int tid = threadIdx.x;
    int w = tid >> 6, lane = tid & 63;
    int l15 = lane & 15, l4 = lane >> 4;
    int beta = blockIdx.x;
    int tile = beta & 31, mh = (beta >> 5) & 1, b = beta >> 6;
    int hw0 = tile * 32;
    int pbase = mh * 128;
    int xrow = tid & 31, cs = tid >> 5;   // hw 0..31, c-octet slot 0..7

    f32x4 pacc[2][2] = {};
    f32x4 gacc[2][2] = {};

    float vb[2][8];
    {   // preload X chunk 0
        const float* xc = xlo + ((size_t)b * 512 + cs * 8) * 1024 + hw0 + xrow;
#pragma unroll
        for (int j = 0; j < 8; j++) vb[0][j] = xc[(size_t)j * 1024];
    }

#pragma unroll
    for (int kc = 0; kc < 8; kc++) {
        int c0 = kc * 64;
        const int cur = kc & 1;
        __syncthreads();
        // stage Wp/Wg chunk [128 rows][64 c] fp32->bf16, granule slot ^= row&7
#pragma unroll
        for (int k = 0; k < 4; k++) {
            int idx = k * 256 + tid;
            int row = idx >> 3, s = idx & 7;
            const float* pp = Wp + (size_t)(pbase + row) * 512 + c0 + s * 8;
            const float* pg = Wg + (size_t)(pbase + row) * 512 + c0 + s * 8;
            float4 a0 = ((const float4*)pp)[0], a1 = ((const float4*)pp)[1];
            float4 b0 = ((const float4*)pg)[0], b1 = ((const float4*)pg)[1];
            u16x8 op = { cvt_bf16(a0.x), cvt_bf16(a0.y), cvt_bf16(a0.z), cvt_bf16(a0.w),
                         cvt_bf16(a1.x), cvt_bf16(a1.y), cvt_bf16(a1.z), cvt_bf16(a1.w) };
            u16x8 og = { cvt_bf16(b0.x), cvt_bf16(b0.y), cvt_bf16(b0.z), cvt_bf16(b0.w),
                         cvt_bf16(b1.x), cvt_bf16(b1.y), cvt_bf16(b1.z), cvt_bf16(b1.w) };
            int off = row * 64 + ((s ^ (row & 7)) << 3);
            *(u16x8*)&sWp[off] = op;
            *(u16x8*)&sWg[off] = og;
        }
        // write prefetched X -> sX1 swizzled
        {
            u16x8 o = { cvt_bf16(vb[cur][0]), cvt_bf16(vb[cur][1]), cvt_bf16(vb[cur][2]),
                        cvt_bf16(vb[cur][3]), cvt_bf16(vb[cur][4]), cvt_bf16(vb[cur][5]),
                        cvt_bf16(vb[cur][6]), cvt_bf16(vb[cur][7]) };
            int phys = cs ^ (xrow & 7);
            *(u16x8*)&sX1[xrow * 64 + phys * 8] = o;
        }
        // prefetch next X chunk (flies under MFMA)
        if (kc < 7) {
            const float* xc = xlo + ((size_t)b * 512 + (c0 + 64) + cs * 8) * 1024 + hw0 + xrow;
#pragma unroll
            for (int j = 0; j < 8; j++) vb[cur ^ 1][j] = xc[(size_t)j * 1024];
        }
        __syncthreads();
#pragma unroll
        for (int kk = 0; kk < 2; kk++) {
            u16x8 bf[2];
#pragma unroll
            for (int ht = 0; ht < 2; ht++) {
                int row = ht * 16 + l15;
                bf[ht] = *(const u16x8*)&sX1[row * 64 + (((kk * 4 + l4) ^ (row & 7)) << 3)];
            }
#pragma unroll
            for (int i = 0; i < 2; i++) {
                int row = w * 32 + i * 16 + l15;
                int off = row * 64 + (((kk * 4 + l4) ^ (row & 7)) << 3);
                u16x8 ap = *(const u16x8*)&sWp[off];
                u16x8 ag = *(const u16x8*)&sWg[off];
#pragma unroll
                for (int ht = 0; ht < 2; ht++) {
                    pacc[i][ht] = mfma16(ap, bf[ht], pacc[i][ht]);
                    gacc[i][ht] = mfma16(ag, bf[ht], gacc[i][ht]);
                }
            }
        }
    }

    float s1 = 0.f, s2 = 0.f;
#pragma unroll
    for (int i = 0; i < 2; i++)
#pragma unroll
        for (int ht = 0; ht < 2; ht++)
#pragma unroll
            for (int r = 0; r < 4; r++) {
                float pv = pacc[i][ht][r], gv = gacc[i][ht][r];
                s1 += pv * gv; s2 += pv * pv * gv;
            }
#pragma unroll
    for (int m = 1; m < 64; m <<= 1) {
        s1 += __shfl_xor(s1, m);
        s2 += __shfl_xor(s2, m);
    }
    if (lane == 0) {
        int g = mh * 4 + w;
        float* dst = att_part + ((size_t)(b * 8 + g) * 32 + tile) * 2;
        dst[0] = s1; dst[1] = s2;
    }
}

// ---------------------------------------------------------------------------
// k1b: one wave per (b,g). Exact fp32 S0 via colsum(Wg)·hwsum(xlo).
// ---------------------------------------------------------------------------
__global__ __launch_bounds__(64)
void k1b_coef(const float* __restrict__ Wg, const float* __restrict__ sxsum,
              const float* __restrict__ att_part, float* __restrict__ coef,
              float a0s, float a1s, float a2s)
{
    int bg = blockIdx.x;
    int b = bg >> 3, g = bg & 7;
    int l = threadIdx.x;
    float s0 = 0.f;
    for (int cc = 0; cc < 512; cc += 64) {
        int c = cc + l;
        float cs = 0.f;
#pragma unroll
        for (int pp = 0; pp < 32; pp++) cs += Wg[(size_t)(g * 32 + pp) * 512 + c];
        s0 += cs * sxsum[(size_t)b * 512 + c];
    }
    float s1 = (l < 32) ? att_part[((size_t)bg * 32 + l) * 2 + 0] : 0.f;
    float s2 = (l < 32) ? att_part[((size_t)bg * 32 + l) * 2 + 1] : 0.f;
#pragma unroll
    for (int m = 1; m < 64; m <<= 1) {
        s0 += __shfl_xor(s0, m);
        s1 += __shfl_xor(s1, m);
        s2 += __shfl_xor(s2, m);
    }
    if (l == 0) {
        coef[bg * 3 + 0] = a0s * s0;
        coef[bg * 3 + 1] = a1s * s1;
        coef[bg * 3 + 2] = a2s * s2;
    }
}

// ---------------------------------------------------------------------------
// k2: t-GEMM (MFMA) -> poly -> grouped conv (MFMA) -> z fp32 + GN partials.
// grid 1024 = (b:16, hwt:64). 256 planes x 64 hw, K=512 (chunks 64).
// LDS 40 KB exactly (4 blocks/CU): sMain 32KB (Wt chunks, then xx), sX 8KB
// (X tile during K-loop; reused as float sR[512] in conv epilogue).
// X tile register-prefetched across chunks (loads stay in flight over
// s_barrier; waitcnt lands at next chunk's ds_write).
// ---------------------------------------------------------------------------
__global__ __launch_bounds__(256, 4)
void k2_main(const float* __restrict__ xhi, const float* __restrict__ Wt,
             const float* __restrict__ Wz, const float* __restrict__ coef,
             float* __restrict__ zout, float* __restrict__ zstat)
{
    __shared__ unsigned short sMain[16384];  // 32 KB
    __shared__ unsigned short sX[4096];      // 8 KB; conv epilogue: float sR[512]

    int tid = threadIdx.x;
    int w = tid >> 6, lane = tid & 63;
    int l15 = lane & 15, l4 = lane >> 4;
    int hwt = blockIdx.x & 63, b = blockIdx.x >> 6;
    int hw0 = hwt * 64;
    int xrow = tid & 63, chalf = tid >> 6;

    float c0v[2], c1v[2], c2v[2];
#pragma unroll
    for (int u = 0; u < 2; u++) {
        const float* cf = coef + (size_t)(b * 8 + 2 * w + u) * 3;
        c0v[u] = cf[0]; c1v[u] = cf[1]; c2v[u] = cf[2];
    }

    f32x4 acc[4][4] = {};

    float vb[2][16];
    {   // preload X chunk 0
        const float* xc = xhi + ((size_t)b * 512 + chalf * 16) * 4096 + hw0 + xrow;
#pragma unroll
        for (int cc = 0; cc < 16; cc++) vb[0][cc] = xc[(size_t)cc * 4096];
    }

#pragma unroll
    for (int kc = 0; kc < 8; kc++) {
        int c0 = kc * 64;
        const int cur = kc & 1;
        __syncthreads();
        // ---- stage Wt chunk [256 rows][64 c] -> sMain, granule slot ^= row&7
#pragma unroll
        for (int k = 0; k < 8; k++) {
            int idx = k * 256 + tid;
            int row = idx >> 3, s = idx & 7;
            const float* sp = Wt + (size_t)row * 512 + c0 + s * 8;
            float4 v0 = ((const float4*)sp)[0];
            float4 v1 = ((const float4*)sp)[1];
            u16x8 o = { cvt_bf16(v0.x), cvt_bf16(v0.y), cvt_bf16(v0.z), cvt_bf16(v0.w),
                        cvt_bf16(v1.x), cvt_bf16(v1.y), cvt_bf16(v1.z), cvt_bf16(v1.w) };
            *(u16x8*)&sMain[row * 64 + ((s ^ (row & 7)) << 3)] = o;
        }
        // ---- write prefetched X -> sX swizzled
#pragma unroll
        for (int h = 0; h < 2; h++) {
            u16x8 o = { cvt_bf16(vb[cur][h*8+0]), cvt_bf16(vb[cur][h*8+1]),
                        cvt_bf16(vb[cur][h*8+2]), cvt_bf16(vb[cur][h*8+3]),
                        cvt_bf16(vb[cur][h*8+4]), cvt_bf16(vb[cur][h*8+5]),
                        cvt_bf16(vb[cur][h*8+6]), cvt_bf16(vb[cur][h*8+7]) };
            int phys = (chalf * 2 + h) ^ (xrow & 7);
            *(u16x8*)&sX[xrow * 64 + phys * 8] = o;
        }
        // ---- prefetch next X chunk (flies under the MFMA phase)
        if (kc < 7) {
            const float* xc = xhi + ((size_t)b * 512 + (c0 + 64) + chalf * 16) * 4096 + hw0 + xrow;
#pragma unroll
            for (int cc = 0; cc < 16; cc++) vb[cur ^ 1][cc] = xc[(size_t)cc * 4096];
        }
        __syncthreads();
#pragma unroll
        for (int kk = 0; kk < 2; kk++) {
            u16x8 bf[4];
#pragma unroll
            for (int ht = 0; ht < 4; ht++) {
                int row = ht * 16 + l15;
                bf[ht] = *(const u16x8*)&sX[row * 64 + (((kk * 4 + l4) ^ (row & 7)) << 3)];
            }
#pragma unroll
            for (int i = 0; i < 4; i++) {
                int row = w * 64 + i * 16 + l15;
                u16x8 af = *(const u16x8*)&sMain[row * 64 + (((kk * 4 + l4) ^ (row & 7)) << 3)];
#pragma unroll
                for (int ht = 0; ht < 4; ht++)
                    acc[i][ht] = mfma16(af, bf[ht], acc[i][ht]);
            }
        }
    }

    // poly in registers: xx = c1*t + c2*t^2
#pragma unroll
    for (int i = 0; i < 4; i++) {
        int u = i >> 1;
#pragma unroll
        for (int ht = 0; ht < 4; ht++) {
            f32x4 t = acc[i][ht];
            acc[i][ht] = c1v[u] * t + c2v[u] * t * t;
        }
    }
    __syncthreads();   // all LDS reads done -> reuse sMain as xx, sX as sR

    // xx -> sMain as [64 hw][256 p] bf16, wave-local granule swizzle
#pragma unroll
    for (int i = 0; i < 4; i++) {
#pragma unroll
        for (int ht = 0; ht < 4; ht++) {
            int row = ht * 16 + l15;
            f32x4 xv = acc[i][ht];
            u16x4 o = { cvt_bf16(xv[0]), cvt_bf16(xv[1]), cvt_bf16(xv[2]), cvt_bf16(xv[3]) };
            int phys = w * 8 + ((i * 2 + (l4 >> 1)) ^ (row & 7));
            *(u16x4*)&sMain[row * 256 + phys * 8 + (l4 & 1) * 4] = o;
        }
    }
    // R[ch] = rowsum(Wz) fp32 -> sR (aliases sX storage; sX dead now)
    float* sR = (float*)sX;
#pragma unroll
    for (int e = 0; e < 2; e++) {
        int ch = tid * 2 + e;
        const float* wr = Wz + (size_t)ch * 32;
        float s = 0.f;
#pragma unroll
        for (int q = 0; q < 8; q++) {
            float4 v = ((const float4*)wr)[q];
            s += v.x + v.y + v.z + v.w;
        }
        sR[ch] = s;
    }
    __syncthreads();

    // grouped conv: z = Wz@xx + c0*R  (wave w: channels [128w, 128w+128))
    u16x8 wzf[8];
#pragma unroll
    for (int ot = 0; ot < 8; ot++) {
        const float* wr = Wz + (size_t)(w * 128 + ot * 16 + l15) * 32 + l4 * 8;
        float4 v0 = ((const float4*)wr)[0];
        float4 v1 = ((const float4*)wr)[1];
        u16x8 o = { cvt_bf16(v0.x), cvt_bf16(v0.y), cvt_bf16(v0.z), cvt_bf16(v0.w),
                    cvt_bf16(v1.x), cvt_bf16(v1.y), cvt_bf16(v1.z), cvt_bf16(v1.w) };
        wzf[ot] = o;
    }

    float s[2] = {0, 0}, s2a[2] = {0, 0};
    f32x4 zero4 = {0.f, 0.f, 0.f, 0.f};
#pragma unroll
    for (int ht = 0; ht < 4; ht++) {
        int row = ht * 16 + l15;
        u16x8 bfr[2];
#pragma unroll
        for (int u = 0; u < 2; u++) {
            int phys = w * 8 + ((u * 4 + l4) ^ (row & 7));
            bfr[u] = *(const u16x8*)&sMain[row * 256 + phys * 8];
        }
#pragma unroll
        for (int ot = 0; ot < 8; ot++) {
            int u = ot >> 2;
            f32x4 z = mfma16(wzf[ot], bfr[u], zero4);
            f32x4 rv = *(const f32x4*)&sR[w * 128 + ot * 16 + l4 * 4];
            z = z + c0v[u] * rv;
            float* zp = zout + ((size_t)(b * 512 + w * 128 + ot * 16 + l4 * 4)) * 4096
                      + hw0 + ht * 16 + l15;
#pragma unroll
            for (int r = 0; r < 4; r++) {
                zp[(size_t)r * 4096] = z[r];
                s[u] += z[r]; s2a[u] += z[r] * z[r];
            }
        }
    }
#pragma unroll
    for (int m = 1; m < 64; m <<= 1) {
#pragma unroll
        for (int u = 0; u < 2; u++) {
            s[u]   += __shfl_xor(s[u], m);
            s2a[u] += __shfl_xor(s2a[u], m);
        }
    }
    if (lane == 0) {
#pragma unroll
        for (int u = 0; u < 2; u++) {
            atomicAdd(&zstat[(size_t)(b * 8 + 2 * w + u) * 2 + 0], s[u]);
            atomicAdd(&zstat[(size_t)(b * 8 + 2 * w + u) * 2 + 1], s2a[u]);
        }
    }
}

__global__ void k2b_gn(const float* __restrict__ zstat, float* __restrict__ gnstat)
{
    int t = threadIdx.x;
    if (t >= 128) return;
    float S = zstat[t * 2], S2 = zstat[t * 2 + 1];
    const float N = 64.0f * 4096.0f;
    float mean = S / N;
    float var = S2 / N - mean * mean;
    var = var < 0.f ? 0.f : var;
    gnstat[t * 2] = mean;
    gnstat[t * 2 + 1] = rsqrtf(var + EPS_);
}

// ---------------------------------------------------------------------------
// k3: out = (z - mean)*rsig*gn_w + gn_b + input_high  (in place on d_out)
// ---------------------------------------------------------------------------
__global__ __launch_bounds__(256)
void k3_final(float* __restrict__ out, const float* __restrict__ xhi,
              const float* __restrict__ gnstat, const float* __restrict__ gnw,
              const float* __restrict__ gnb)
{
#pragma unroll
    for (int k = 0; k < 4; k++) {
        size_t idx = (size_t)blockIdx.x * 1024 + (size_t)k * 256 + threadIdx.x; // f4 index
        size_t e = idx * 4;
        int ch = (int)((e >> 12) & 511);
        int b  = (int)(e >> 21);
        int gg = ch >> 6;
        const float* gs = gnstat + (size_t)(b * 8 + gg) * 2;
        float mean = gs[0];
        float w = gnw[ch] * gs[1];
        float bb = gnb[ch];
        float4 z = ((const float4*)out)[idx];
        float4 xv = ((const float4*)xhi)[idx];
        float4 r;
        r.x = (z.x - mean) * w + bb + xv.x;
        r.y = (z.y - mean) * w + bb + xv.y;
        r.z = (z.z - mean) * w + bb + xv.z;
        r.w = (z.w - mean) * w + bb + xv.w;
        ((float4*)out)[idx] = r;
    }
}

extern "C" void kernel_launch(void* const* d_in, const int* in_sizes, int n_in,
                              void* d_out, int out_size, void* d_ws, size_t ws_size,
                              hipStream_t stream) {
    (void)in_sizes; (void)n_in; (void)out_size; (void)ws_size;
    const float* xhi = (const float*)d_in[0];
    const float* xlo = (const float*)d_in[1];
    const float* Wt  = (const float*)d_in[2];
    const float* Wp  = (const float*)d_in[3];
    const float* Wg  = (const float*)d_in[4];
    const float* Wz  = (const float*)d_in[5];
    const float* gnw = (const float*)d_in[6];
    const float* gnb = (const float*)d_in[7];
    float* out = (float*)d_out;
    float* ws  = (float*)d_ws;

    float* sxsum    = ws;              // 8192 floats
    float* att_part = ws + 8192;       // 8192 (128 bg x 32 tiles x 2)
    float* coef     = ws + 16384;      // 384
    float* zstat    = ws + 16768;      // 256 (128 x {S, S2})
    float* gnstat   = ws + 17024;      // 256   -> total 17280 f = 69.1 KB

    // alpha_k^2 = (2*gamma)^k / k! * exp(-2*gamma), gamma = 1e-4
    double g2 = 2.0e-4;
    double ee = exp(-g2);
    float a0s = (float)ee;
    float a1s = (float)(g2 * ee);
    float a2s = (float)(g2 * g2 * 0.5 * ee);

    k0s     <<<dim3(256),  dim3(256), 0, stream>>>(xlo, sxsum);
    k1_att  <<<dim3(1024), dim3(256), 0, stream>>>(xlo, Wp, Wg, att_part);
    k1b_coef<<<dim3(128),  dim3(64),  0, stream>>>(Wg, sxsum, att_part, coef, a0s, a1s, a2s);
    hipMemsetAsync(zstat, 0, 256 * sizeof(float), stream);
    k2_main <<<dim3(1024), dim3(256), 0, stream>>>(xhi, Wt, Wz, coef, out, zstat);
    k2b_gn  <<<dim3(1),    dim3(128), 0, stream>>>(zstat, gnstat);
    k3_final<<<dim3(8192), dim3(256), 0, stream>>>(out, xhi, gnstat, gnw, gnb);
}

// Round 7
// 243.050 us; speedup vs baseline: 1.8727x; 1.0981x over previous
//
#include <hip/hip_runtime.h>
#include <math.h>

typedef __attribute__((ext_vector_type(8))) short short8;
typedef __attribute__((ext_vector_type(8))) unsigned short u16x8;
typedef __attribute__((ext_vector_type(4))) float f32x4;

#define EPS_ 1e-5f

__device__ inline unsigned int cvtpk(float a, float b) {
    unsigned int r;
    asm("v_cvt_pk_bf16_f32 %0, %1, %2" : "=v"(r) : "v"(a), "v"(b));
    return r;
}

__device__ inline f32x4 mfma16(u16x8 a, u16x8 b, f32x4 c) {
    return __builtin_amdgcn_mfma_f32_16x16x32_bf16((short8)a, (short8)b, c, 0, 0, 0);
}

// ---------------------------------------------------------------------------
// k0s: sxsum[b][c] = sum_hw xlo[b][c][:]   (exact fp32, feeds exact S0)
// ---------------------------------------------------------------------------
__global__ __launch_bounds__(256)
void k0s(const float* __restrict__ xlo, float* __restrict__ sxsum)
{
    __shared__ float sred[256];
    int blk = blockIdx.x;
    int cgrp = blk & 15, b = blk >> 4;
    int tid = threadIdx.x;
    int cl = tid >> 3, seg = tid & 7;
    int c = cgrp * 32 + cl;
    const float* row = xlo + ((size_t)b * 512 + c) * 1024 + seg * 128;
    float s = 0.f;
#pragma unroll
    for (int i = 0; i < 32; i++) {
        float4 v = ((const float4*)row)[i];
        s += v.x + v.y + v.z + v.w;
    }
    sred[tid] = s;
    __syncthreads();
    if (seg == 0) {
        float t = 0.f;
#pragma unroll
        for (int e = 0; e < 8; e++) t += sred[cl * 8 + e];
        sxsum[(size_t)b * 512 + c] = t;
    }
}

// ---------------------------------------------------------------------------
// k1: MFMA p/g projections -> S1,S2 partials.
// grid 1024 = (b:16, mh:2, tile:32); block = 128 planes x 32 hw, K=512 (8x64).
// Wave w owns group g = mh*4+w. Named vbA/vbB ping-pong (no runtime indexing),
// cvt_pk staging, prefetch issued at top of each chunk body.
// ---------------------------------------------------------------------------
#define K1_BODY(C0, VCUR, VNXT, DOPREF)                                          \
  {                                                                              \
    if (DOPREF) {                                                                \
        const float* xc = xlo + ((size_t)b * 512 + (C0) + 64 + cs * 8) * 1024 + hw0 + xrow; \
        _Pragma("unroll")                                                        \
        for (int j = 0; j < 8; j++) VNXT[j] = xc[(size_t)j * 1024];              \
    }                                                                            \
    __syncthreads();                                                             \
    _Pragma("unroll")                                                            \
    for (int k = 0; k < 4; k++) {                                                \
        int idx = k * 256 + tid;                                                 \
        int row = idx >> 3, s = idx & 7;                                         \
        const float* pp = Wp + (size_t)(pbase + row) * 512 + (C0) + s * 8;       \
        const float* pg = Wg + (size_t)(pbase + row) * 512 + (C0) + s * 8;       \
        float4 a0 = ((const float4*)pp)[0], a1 = ((const float4*)pp)[1];         \
        float4 b0 = ((const float4*)pg)[0], b1 = ((const float4*)pg)[1];         \
        uint4 qp = { cvtpk(a0.x,a0.y), cvtpk(a0.z,a0.w),                         \
                     cvtpk(a1.x,a1.y), cvtpk(a1.z,a1.w) };                       \
        uint4 qg = { cvtpk(b0.x,b0.y), cvtpk(b0.z,b0.w),                         \
                     cvtpk(b1.x,b1.y), cvtpk(b1.z,b1.w) };                       \
        int off = row * 64 + ((s ^ (row & 7)) << 3);                             \
        *(uint4*)&sWp[off] = qp;                                                 \
        *(uint4*)&sWg[off] = qg;                                                 \
    }                                                                            \
    {                                                                            \
        uint4 q = { cvtpk(VCUR[0],VCUR[1]), cvtpk(VCUR[2],VCUR[3]),              \
                    cvtpk(VCUR[4],VCUR[5]), cvtpk(VCUR[6],VCUR[7]) };            \
        int phys = cs ^ (xrow & 7);                                              \
        *(uint4*)&sX1[xrow * 64 + phys * 8] = q;                                 \
    }                                                                            \
    __syncthreads();                                                             \
    _Pragma("unroll")                                                            \
    for (int kk = 0; kk < 2; kk++) {                                             \
        u16x8 bf[2];                                                             \
        _Pragma("unroll")                                                        \
        for (int ht = 0; ht < 2; ht++) {                                         \
            int row = ht * 16 + l15;                                             \
            bf[ht] = *(const u16x8*)&sX1[row * 64 + (((kk*4+l4) ^ (row&7)) << 3)]; \
        }                                                                        \
        _Pragma("unroll")                                                        \
        for (int i = 0; i < 2; i++) {                                            \
            int row = w * 32 + i * 16 + l15;                                     \
            int off = row * 64 + (((kk*4+l4) ^ (row&7)) << 3);                   \
            u16x8 ap = *(const u16x8*)&sWp[off];                                 \
            u16x8 ag = *(const u16x8*)&sWg[off];                                 \
            _Pragma("unroll")                                                    \
            for (int ht = 0; ht < 2; ht++) {                                     \
                pacc[i][ht] = mfma16(ap, bf[ht], pacc[i][ht]);                   \
                gacc[i][ht] = mfma16(ag, bf[ht], gacc[i][ht]);                   \
            }                                                                    \
        }                                                                        \
    }                                                                            \
  }

__global__ __launch_bounds__(256, 4)
void k1_att(const float* __restrict__ xlo, const float* __restrict__ Wp,
            const float* __restrict__ Wg, float* __restrict__ att_part)
{
    __shared__ unsigned short sWp[8192];   // 16 KB [128 rows][64 c] swizzled
    __shared__ unsigned short sWg[8192];   // 16 KB
    __shared__ unsigned short sX1[2048];   // 4 KB  [32 hw][64 c] swizzled

    int tid = threadIdx.x;
    int w = tid >> 6, lane = tid & 63;
    int l15 = lane & 15, l4 = lane >> 4;
    int beta = blockIdx.x;
    int tile = beta & 31, mh = (beta >> 5) & 1, b = beta >> 6;
    int hw0 = tile * 32;
    int pbase = mh * 128;
    int xrow = tid & 31, cs = tid >> 5;   // hw 0..31, c-octet slot 0..7

    f32x4 pacc[2][2] = {};
    f32x4 gacc[2][2] = {};

    float vbA[8], vbB[8];
    {   // preload X chunk 0
        const float* xc = xlo + ((size_t)b * 512 + cs * 8) * 1024 + hw0 + xrow;
#pragma unroll
        for (int j = 0; j < 8; j++) vbA[j] = xc[(size_t)j * 1024];
    }

    for (int kc2 = 0; kc2 < 4; kc2++) {
        int c0 = kc2 * 128;
        K1_BODY(c0,      vbA, vbB, true);
        K1_BODY(c0 + 64, vbB, vbA, (kc2 < 3));
    }

    float s1 = 0.f, s2 = 0.f;
#pragma unroll
    for (int i = 0; i < 2; i++)
#pragma unroll
        for (int ht = 0; ht < 2; ht++)
#pragma unroll
            for (int r = 0; r < 4; r++) {
                float pv = pacc[i][ht][r], gv = gacc[i][ht][r];
                s1 += pv * gv; s2 += pv * pv * gv;
            }
#pragma unroll
    for (int m = 1; m < 64; m <<= 1) {
        s1 += __shfl_xor(s1, m);
        s2 += __shfl_xor(s2, m);
    }
    if (lane == 0) {
        int g = mh * 4 + w;
        float* dst = att_part + ((size_t)(b * 8 + g) * 32 + tile) * 2;
        dst[0] = s1; dst[1] = s2;
    }
}

// ---------------------------------------------------------------------------
// k1b: one wave per (b,g). Exact fp32 S0 via colsum(Wg)·hwsum(xlo).
// ---------------------------------------------------------------------------
__global__ __launch_bounds__(64)
void k1b_coef(const float* __restrict__ Wg, const float* __restrict__ sxsum,
              const float* __restrict__ att_part, float* __restrict__ coef,
              float a0s, float a1s, float a2s)
{
    int bg = blockIdx.x;
    int b = bg >> 3, g = bg & 7;
    int l = threadIdx.x;
    float s0 = 0.f;
    for (int cc = 0; cc < 512; cc += 64) {
        int c = cc + l;
        float cs = 0.f;
#pragma unroll
        for (int pp = 0; pp < 32; pp++) cs += Wg[(size_t)(g * 32 + pp) * 512 + c];
        s0 += cs * sxsum[(size_t)b * 512 + c];
    }
    float s1 = (l < 32) ? att_part[((size_t)bg * 32 + l) * 2 + 0] : 0.f;
    float s2 = (l < 32) ? att_part[((size_t)bg * 32 + l) * 2 + 1] : 0.f;
#pragma unroll
    for (int m = 1; m < 64; m <<= 1) {
        s0 += __shfl_xor(s0, m);
        s1 += __shfl_xor(s1, m);
        s2 += __shfl_xor(s2, m);
    }
    if (l == 0) {
        coef[bg * 3 + 0] = a0s * s0;
        coef[bg * 3 + 1] = a1s * s1;
        coef[bg * 3 + 2] = a2s * s2;
    }
}

// ---------------------------------------------------------------------------
// k2: t-GEMM (MFMA) -> poly -> grouped conv (MFMA) -> z fp32 + GN partials.
// grid 1024 = (b:16, hwt:64), 512 threads (8 waves). Wave w: t-planes
// [32w,32w+32); conv channels = group w. acc = 8 f32x4 (32 AGPR) -> fits
// 4 waves/SIMD without spills. LDS 40 KB (2 blocks/CU, 16 waves).
// Named vbA/vbB ping-pong prefetch; cvt_pk staging.
// ---------------------------------------------------------------------------
#define K2_BODY(C0, VCUR, VNXT, DOPREF)                                          \
  {                                                                              \
    if (DOPREF) {                                                                \
        const float* xc = xhi + ((size_t)b * 512 + (C0) + 64 + w * 8) * 4096 + hw0 + xrow; \
        _Pragma("unroll")                                                        \
        for (int j = 0; j < 8; j++) VNXT[j] = xc[(size_t)j * 4096];              \
    }                                                                            \
    __syncthreads();                                                             \
    _Pragma("unroll")                                                            \
    for (int k = 0; k < 4; k++) {                                                \
        int idx = k * 512 + tid;                                                 \
        int row = idx >> 3, s = idx & 7;                                         \
        const float* sp = Wt + (size_t)row * 512 + (C0) + s * 8;                 \
        float4 v0 = ((const float4*)sp)[0];                                      \
        float4 v1 = ((const float4*)sp)[1];                                      \
        uint4 q = { cvtpk(v0.x,v0.y), cvtpk(v0.z,v0.w),                          \
                    cvtpk(v1.x,v1.y), cvtpk(v1.z,v1.w) };                        \
        *(uint4*)&sMain[row * 64 + ((s ^ (row & 7)) << 3)] = q;                  \
    }                                                                            \
    {                                                                            \
        uint4 q = { cvtpk(VCUR[0],VCUR[1]), cvtpk(VCUR[2],VCUR[3]),              \
                    cvtpk(VCUR[4],VCUR[5]), cvtpk(VCUR[6],VCUR[7]) };            \
        int phys = w ^ (xrow & 7);                                               \
        *(uint4*)&sX[xrow * 64 + phys * 8] = q;                                  \
    }                                                                            \
    __syncthreads();                                                             \
    _Pragma("unroll")                                                            \
    for (int kk = 0; kk < 2; kk++) {                                             \
        u16x8 bf[4];                                                             \
        _Pragma("unroll")                                                        \
        for (int ht = 0; ht < 4; ht++) {                                         \
            int row = ht * 16 + l15;                                             \
            bf[ht] = *(const u16x8*)&sX[row * 64 + (((kk*4+l4) ^ (row&7)) << 3)]; \
        }                                                                        \
        _Pragma("unroll")                                                        \
        for (int i = 0; i < 2; i++) {                                            \
            int row = w * 32 + i * 16 + l15;                                     \
            u16x8 af = *(const u16x8*)&sMain[row * 64 + (((kk*4+l4) ^ (row&7)) << 3)]; \
            _Pragma("unroll")                                                    \
            for (int ht = 0; ht < 4; ht++)                                       \
                acc[i][ht] = mfma16(af, bf[ht], acc[i][ht]);                     \
        }                                                                        \
    }                                                                            \
  }

__global__ __launch_bounds__(512, 4)
void k2_main(const float* __restrict__ xhi, const float* __restrict__ Wt,
             const float* __restrict__ Wz, const float* __restrict__ coef,
             float* __restrict__ zout, float* __restrict__ zstat)
{
    __shared__ unsigned short sMain[16384];  // 32 KB: Wt chunks, then xx[64hw][256p]
    __shared__ unsigned short sX[4096];      // 8 KB: X tile; epilogue: float sR[512]

    int tid = threadIdx.x;
    int w = tid >> 6, lane = tid & 63;       // w = wave = group = c-octet
    int l15 = lane & 15, l4 = lane >> 4;
    int hwt = blockIdx.x & 63, b = blockIdx.x >> 6;
    int hw0 = hwt * 64;
    int xrow = tid & 63;

    const float* cf = coef + (size_t)(b * 8 + w) * 3;
    float c0v = cf[0], c1v = cf[1], c2v = cf[2];

    f32x4 acc[2][4] = {};

    float vbA[8], vbB[8];
    {   // preload X chunk 0
        const float* xc = xhi + ((size_t)b * 512 + w * 8) * 4096 + hw0 + xrow;
#pragma unroll
        for (int j = 0; j < 8; j++) vbA[j] = xc[(size_t)j * 4096];
    }

    for (int kc2 = 0; kc2 < 4; kc2++) {
        int c0 = kc2 * 128;
        K2_BODY(c0,      vbA, vbB, true);
        K2_BODY(c0 + 64, vbB, vbA, (kc2 < 3));
    }

    // poly in registers: xx = c1*t + c2*t^2 (wave w = group w)
#pragma unroll
    for (int i = 0; i < 2; i++)
#pragma unroll
        for (int ht = 0; ht < 4; ht++) {
            f32x4 t = acc[i][ht];
            acc[i][ht] = c1v * t + c2v * t * t;
        }
    __syncthreads();   // all LDS reads done -> reuse sMain as xx, sX as sR

    // xx -> sMain as [64 hw][256 p] bf16; wave granules [4w,4w+4), swz ^(row&3)
#pragma unroll
    for (int i = 0; i < 2; i++)
#pragma unroll
        for (int ht = 0; ht < 4; ht++) {
            int row = ht * 16 + l15;
            f32x4 xv = acc[i][ht];
            uint2 q = { cvtpk(xv[0], xv[1]), cvtpk(xv[2], xv[3]) };
            int phys = w * 4 + ((i * 2 + (l4 >> 1)) ^ (row & 3));
            *(uint2*)&sMain[row * 256 + phys * 8 + (l4 & 1) * 4] = q;
        }

    // R[ch] = rowsum(Wz) fp32 -> sR (aliases sX; 1 channel per thread)
    float* sR = (float*)sX;
    {
        const float* wr = Wz + (size_t)tid * 32;
        float s = 0.f;
#pragma unroll
        for (int q = 0; q < 8; q++) {
            float4 v = ((const float4*)wr)[q];
            s += v.x + v.y + v.z + v.w;
        }
        sR[tid] = s;
    }

    // Wz fragments for group w (4 ot covers 64 channels)
    u16x8 wzf[4];
#pragma unroll
    for (int ot = 0; ot < 4; ot++) {
        const float* wr = Wz + (size_t)(w * 64 + ot * 16 + l15) * 32 + l4 * 8;
        float4 v0 = ((const float4*)wr)[0];
        float4 v1 = ((const float4*)wr)[1];
        uint4 q = { cvtpk(v0.x,v0.y), cvtpk(v0.z,v0.w),
                    cvtpk(v1.x,v1.y), cvtpk(v1.z,v1.w) };
        wzf[ot] = *(u16x8*)&q;
    }
    __syncthreads();

    // grouped conv: z = Wz@xx + c0*R  (wave w handles group w, 64 ch x 64 hw)
    float s = 0.f, s2a = 0.f;
    f32x4 zero4 = {0.f, 0.f, 0.f, 0.f};
#pragma unroll
    for (int ht = 0; ht < 4; ht++) {
        int row = ht * 16 + l15;
        u16x8 bfr = *(const u16x8*)&sMain[row * 256 + (w * 4 + (l4 ^ (row & 3))) * 8];
#pragma unroll
        for (int ot = 0; ot < 4; ot++) {
            f32x4 z = mfma16(wzf[ot], bfr, zero4);
            f32x4 rv = *(const f32x4*)&sR[w * 64 + ot * 16 + l4 * 4];
            z = z + c0v * rv;
            float* zp = zout + ((size_t)(b * 512 + w * 64 + ot * 16 + l4 * 4)) * 4096
                      + hw0 + ht * 16 + l15;
#pragma unroll
            for (int r = 0; r < 4; r++) {
                zp[(size_t)r * 4096] = z[r];
                s += z[r]; s2a += z[r] * z[r];
            }
        }
    }
#pragma unroll
    for (int m = 1; m < 64; m <<= 1) {
        s   += __shfl_xor(s, m);
        s2a += __shfl_xor(s2a, m);
    }
    if (lane == 0) {
        atomicAdd(&zstat[(size_t)(b * 8 + w) * 2 + 0], s);
        atomicAdd(&zstat[(size_t)(b * 8 + w) * 2 + 1], s2a);
    }
}

__global__ void k2b_gn(const float* __restrict__ zstat, float* __restrict__ gnstat)
{
    int t = threadIdx.x;
    if (t >= 128) return;
    float S = zstat[t * 2], S2 = zstat[t * 2 + 1];
    const float N = 64.0f * 4096.0f;
    float mean = S / N;
    float var = S2 / N - mean * mean;
    var = var < 0.f ? 0.f : var;
    gnstat[t * 2] = mean;
    gnstat[t * 2 + 1] = rsqrtf(var + EPS_);
}

// ---------------------------------------------------------------------------
// k3: out = (z - mean)*rsig*gn_w + gn_b + input_high  (in place on d_out)
// ---------------------------------------------------------------------------
__global__ __launch_bounds__(256)
void k3_final(float* __restrict__ out, const float* __restrict__ xhi,
              const float* __restrict__ gnstat, const float* __restrict__ gnw,
              const float* __restrict__ gnb)
{
#pragma unroll
    for (int k = 0; k < 4; k++) {
        size_t idx = (size_t)blockIdx.x * 1024 + (size_t)k * 256 + threadIdx.x; // f4 index
        size_t e = idx * 4;
        int ch = (int)((e >> 12) & 511);
        int b  = (int)(e >> 21);
        int gg = ch >> 6;
        const float* gs = gnstat + (size_t)(b * 8 + gg) * 2;
        float mean = gs[0];
        float w = gnw[ch] * gs[1];
        float bb = gnb[ch];
        float4 z = ((const float4*)out)[idx];
        float4 xv = ((const float4*)xhi)[idx];
        float4 r;
        r.x = (z.x - mean) * w + bb + xv.x;
        r.y = (z.y - mean) * w + bb + xv.y;
        r.z = (z.z - mean) * w + bb + xv.z;
        r.w = (z.w - mean) * w + bb + xv.w;
        ((float4*)out)[idx] = r;
    }
}

extern "C" void kernel_launch(void* const* d_in, const int* in_sizes, int n_in,
                              void* d_out, int out_size, void* d_ws, size_t ws_size,
                              hipStream_t stream) {
    (void)in_sizes; (void)n_in; (void)out_size; (void)ws_size;
    const float* xhi = (const float*)d_in[0];
    const float* xlo = (const float*)d_in[1];
    const float* Wt  = (const float*)d_in[2];
    const float* Wp  = (const float*)d_in[3];
    const float* Wg  = (const float*)d_in[4];
    const float* Wz  = (const float*)d_in[5];
    const float* gnw = (const float*)d_in[6];
    const float* gnb = (const float*)d_in[7];
    float* out = (float*)d_out;
    float* ws  = (float*)d_ws;

    float* sxsum    = ws;              // 8192 floats
    float* att_part = ws + 8192;       // 8192 (128 bg x 32 tiles x 2)
    float* coef     = ws + 16384;      // 384
    float* zstat    = ws + 16768;      // 256 (128 x {S, S2})
    float* gnstat   = ws + 17024;      // 256   -> total 17280 f = 69.1 KB

    // alpha_k^2 = (2*gamma)^k / k! * exp(-2*gamma), gamma = 1e-4
    double g2 = 2.0e-4;
    double ee = exp(-g2);
    float a0s = (float)ee;
    float a1s = (float)(g2 * ee);
    float a2s = (float)(g2 * g2 * 0.5 * ee);

    k0s     <<<dim3(256),  dim3(256), 0, stream>>>(xlo, sxsum);
    k1_att  <<<dim3(1024), dim3(256), 0, stream>>>(xlo, Wp, Wg, att_part);
    k1b_coef<<<dim3(128),  dim3(64),  0, stream>>>(Wg, sxsum, att_part, coef, a0s, a1s, a2s);
    hipMemsetAsync(zstat, 0, 256 * sizeof(float), stream);
    k2_main <<<dim3(1024), dim3(512), 0, stream>>>(xhi, Wt, Wz, coef, out, zstat);
    k2b_gn  <<<dim3(1),    dim3(128), 0, stream>>>(zstat, gnstat);
    k3_final<<<dim3(8192), dim3(256), 0, stream>>>(out, xhi, gnstat, gnw, gnb);
}

// Round 8
// 212.574 us; speedup vs baseline: 2.1412x; 1.1434x over previous
//
#include <hip/hip_runtime.h>
#include <math.h>

typedef __attribute__((ext_vector_type(8))) short short8;
typedef __attribute__((ext_vector_type(8))) unsigned short u16x8;
typedef __attribute__((ext_vector_type(4))) float f32x4;

#define EPS_ 1e-5f

__device__ inline unsigned int cvtpk(float a, float b) {
    unsigned int r;
    asm("v_cvt_pk_bf16_f32 %0, %1, %2" : "=v"(r) : "v"(a), "v"(b));
    return r;
}

__device__ inline f32x4 mfma16(u16x8 a, u16x8 b, f32x4 c) {
    return __builtin_amdgcn_mfma_f32_16x16x32_bf16((short8)a, (short8)b, c, 0, 0, 0);
}

// async global->LDS 16B copy (dest = wave-uniform base + lane*16)
__device__ inline void gll16(const unsigned short* g, unsigned short* l) {
    __builtin_amdgcn_global_load_lds(
        (const __attribute__((address_space(1))) unsigned int*)g,
        (__attribute__((address_space(3))) unsigned int*)l, 16, 0, 0);
}

// ---------------------------------------------------------------------------
// k0s: sxsum[b][c] = sum_hw xlo[b][c][:]   (exact fp32, feeds exact S0)
// ---------------------------------------------------------------------------
__global__ __launch_bounds__(256)
void k0s(const float* __restrict__ xlo, float* __restrict__ sxsum)
{
    __shared__ float sred[256];
    int blk = blockIdx.x;
    int cgrp = blk & 15, b = blk >> 4;
    int tid = threadIdx.x;
    int cl = tid >> 3, seg = tid & 7;
    int c = cgrp * 32 + cl;
    const float* row = xlo + ((size_t)b * 512 + c) * 1024 + seg * 128;
    float s = 0.f;
#pragma unroll
    for (int i = 0; i < 32; i++) {
        float4 v = ((const float4*)row)[i];
        s += v.x + v.y + v.z + v.w;
    }
    sred[tid] = s;
    __syncthreads();
    if (seg == 0) {
        float t = 0.f;
#pragma unroll
        for (int e = 0; e < 8; e++) t += sred[cl * 8 + e];
        sxsum[(size_t)b * 512 + c] = t;
    }
}

// ---------------------------------------------------------------------------
// k0w_t: Wt fp32 -> bf16, chunk-tiled + pre-swizzled so a LINEAR 32KB
// global_load_lds of chunk kc lands XOR-swizzled in LDS:
//   wtb granule (kc, row*8+s) = Wt[row][kc*64 + ((s^(row&7))*8) + 0..7]
// ---------------------------------------------------------------------------
__global__ __launch_bounds__(256)
void k0w_t(const float* __restrict__ Wt, unsigned short* __restrict__ wtb)
{
    int blk = blockIdx.x, tid = threadIdx.x;
    int kc = blk >> 3, sub = blk & 7;
    int idx = sub * 256 + tid;
    int row = idx >> 3, s = idx & 7;
    int colbase = kc * 64 + ((s ^ (row & 7)) << 3);
    const float* sp = Wt + (size_t)row * 512 + colbase;
    float4 v0 = ((const float4*)sp)[0];
    float4 v1 = ((const float4*)sp)[1];
    uint4 q = { cvtpk(v0.x, v0.y), cvtpk(v0.z, v0.w),
                cvtpk(v1.x, v1.y), cvtpk(v1.z, v1.w) };
    *(uint4*)&wtb[(size_t)(kc * 2048 + idx) * 8] = q;
}

// ---------------------------------------------------------------------------
// k1: MFMA p/g projections -> S1,S2 partials (frozen from r7).
// ---------------------------------------------------------------------------
#define K1_BODY(C0, VCUR, VNXT, DOPREF)                                          \
  {                                                                              \
    if (DOPREF) {                                                                \
        const float* xc = xlo + ((size_t)b * 512 + (C0) + 64 + cs * 8) * 1024 + hw0 + xrow; \
        _Pragma("unroll")                                                        \
        for (int j = 0; j < 8; j++) VNXT[j] = xc[(size_t)j * 1024];              \
    }                                                                            \
    __syncthreads();                                                             \
    _Pragma("unroll")                                                            \
    for (int k = 0; k < 4; k++) {                                                \
        int idx = k * 256 + tid;                                                 \
        int row = idx >> 3, s = idx & 7;                                         \
        const float* pp = Wp + (size_t)(pbase + row) * 512 + (C0) + s * 8;       \
        const float* pg = Wg + (size_t)(pbase + row) * 512 + (C0) + s * 8;       \
        float4 a0 = ((const float4*)pp)[0], a1 = ((const float4*)pp)[1];         \
        float4 b0 = ((const float4*)pg)[0], b1 = ((const float4*)pg)[1];         \
        uint4 qp = { cvtpk(a0.x,a0.y), cvtpk(a0.z,a0.w),                         \
                     cvtpk(a1.x,a1.y), cvtpk(a1.z,a1.w) };                       \
        uint4 qg = { cvtpk(b0.x,b0.y), cvtpk(b0.z,b0.w),                         \
                     cvtpk(b1.x,b1.y), cvtpk(b1.z,b1.w) };                       \
        int off = row * 64 + ((s ^ (row & 7)) << 3);                             \
        *(uint4*)&sWp[off] = qp;                                                 \
        *(uint4*)&sWg[off] = qg;                                                 \
    }                                                                            \
    {                                                                            \
        uint4 q = { cvtpk(VCUR[0],VCUR[1]), cvtpk(VCUR[2],VCUR[3]),              \
                    cvtpk(VCUR[4],VCUR[5]), cvtpk(VCUR[6],VCUR[7]) };            \
        int phys = cs ^ (xrow & 7);                                              \
        *(uint4*)&sX1[xrow * 64 + phys * 8] = q;                                 \
    }                                                                            \
    __syncthreads();                                                             \
    _Pragma("unroll")                                                            \
    for (int kk = 0; kk < 2; kk++) {                                             \
        u16x8 bf[2];                                                             \
        _Pragma("unroll")                                                        \
        for (int ht = 0; ht < 2; ht++) {                                         \
            int row = ht * 16 + l15;                                             \
            bf[ht] = *(const u16x8*)&sX1[row * 64 + (((kk*4+l4) ^ (row&7)) << 3)]; \
        }                                                                        \
        _Pragma("unroll")                                                        \
        for (int i = 0; i < 2; i++) {                                            \
            int row = w * 32 + i * 16 + l15;                                     \
            int off = row * 64 + (((kk*4+l4) ^ (row&7)) << 3);                   \
            u16x8 ap = *(const u16x8*)&sWp[off];                                 \
            u16x8 ag = *(const u16x8*)&sWg[off];                                 \
            _Pragma("unroll")                                                    \
            for (int ht = 0; ht < 2; ht++) {                                     \
                pacc[i][ht] = mfma16(ap, bf[ht], pacc[i][ht]);                   \
                gacc[i][ht] = mfma16(ag, bf[ht], gacc[i][ht]);                   \
            }                                                                    \
        }                                                                        \
    }                                                                            \
  }

__global__ __launch_bounds__(256, 4)
void k1_att(const float* __restrict__ xlo, const float* __restrict__ Wp,
            const float* __restrict__ Wg, float* __restrict__ att_part)
{
    __shared__ unsigned short sWp[8192];
    __shared__ unsigned short sWg[8192];
    __shared__ unsigned short sX1[2048];

    int tid = threadIdx.x;
    int w = tid >> 6, lane = tid & 63;
    int l15 = lane & 15, l4 = lane >> 4;
    int beta = blockIdx.x;
    int tile = beta & 31, mh = (beta >> 5) & 1, b = beta >> 6;
    int hw0 = tile * 32;
    int pbase = mh * 128;
    int xrow = tid & 31, cs = tid >> 5;

    f32x4 pacc[2][2] = {};
    f32x4 gacc[2][2] = {};

    float vbA[8], vbB[8];
    {
        const float* xc = xlo + ((size_t)b * 512 + cs * 8) * 1024 + hw0 + xrow;
#pragma unroll
        for (int j = 0; j < 8; j++) vbA[j] = xc[(size_t)j * 1024];
    }

    for (int kc2 = 0; kc2 < 4; kc2++) {
        int c0 = kc2 * 128;
        K1_BODY(c0,      vbA, vbB, true);
        K1_BODY(c0 + 64, vbB, vbA, (kc2 < 3));
    }

    float s1 = 0.f, s2 = 0.f;
#pragma unroll
    for (int i = 0; i < 2; i++)
#pragma unroll
        for (int ht = 0; ht < 2; ht++)
#pragma unroll
            for (int r = 0; r < 4; r++) {
                float pv = pacc[i][ht][r], gv = gacc[i][ht][r];
                s1 += pv * gv; s2 += pv * pv * gv;
            }
#pragma unroll
    for (int m = 1; m < 64; m <<= 1) {
        s1 += __shfl_xor(s1, m);
        s2 += __shfl_xor(s2, m);
    }
    if (lane == 0) {
        int g = mh * 4 + w;
        float* dst = att_part + ((size_t)(b * 8 + g) * 32 + tile) * 2;
        dst[0] = s1; dst[1] = s2;
    }
}

// ---------------------------------------------------------------------------
// k1b: one wave per (b,g). Exact fp32 S0 via colsum(Wg)·hwsum(xlo).
// ---------------------------------------------------------------------------
__global__ __launch_bounds__(64)
void k1b_coef(const float* __restrict__ Wg, const float* __restrict__ sxsum,
              const float* __restrict__ att_part, float* __restrict__ coef,
              float a0s, float a1s, float a2s)
{
    int bg = blockIdx.x;
    int b = bg >> 3, g = bg & 7;
    int l = threadIdx.x;
    float s0 = 0.f;
    for (int cc = 0; cc < 512; cc += 64) {
        int c = cc + l;
        float cs = 0.f;
#pragma unroll
        for (int pp = 0; pp < 32; pp++) cs += Wg[(size_t)(g * 32 + pp) * 512 + c];
        s0 += cs * sxsum[(size_t)b * 512 + c];
    }
    float s1 = (l < 32) ? att_part[((size_t)bg * 32 + l) * 2 + 0] : 0.f;
    float s2 = (l < 32) ? att_part[((size_t)bg * 32 + l) * 2 + 1] : 0.f;
#pragma unroll
    for (int m = 1; m < 64; m <<= 1) {
        s0 += __shfl_xor(s0, m);
        s1 += __shfl_xor(s1, m);
        s2 += __shfl_xor(s2, m);
    }
    if (l == 0) {
        coef[bg * 3 + 0] = a0s * s0;
        coef[bg * 3 + 1] = a1s * s1;
        coef[bg * 3 + 2] = a2s * s2;
    }
}

// ===========================================================================
// k2 shared epilogue (poly -> xx in LDS -> grouped conv -> z + stats)
// ===========================================================================
#define K2_EPILOGUE                                                              \
    _Pragma("unroll")                                                            \
    for (int i = 0; i < 2; i++)                                                  \
        _Pragma("unroll")                                                        \
        for (int ht = 0; ht < 4; ht++) {                                         \
            f32x4 t = acc[i][ht];                                                \
            acc[i][ht] = c1v * t + c2v * t * t;                                  \
        }                                                                        \
    __syncthreads();                                                             \
    _Pragma("unroll")                                                            \
    for (int i = 0; i < 2; i++)                                                  \
        _Pragma("unroll")                                                        \
        for (int ht = 0; ht < 4; ht++) {                                         \
            int row = ht * 16 + l15;                                             \
            f32x4 xv = acc[i][ht];                                               \
            uint2 q = { cvtpk(xv[0], xv[1]), cvtpk(xv[2], xv[3]) };              \
            int phys = w * 4 + ((i * 2 + (l4 >> 1)) ^ (row & 3));                \
            *(uint2*)&sMain[row * 256 + phys * 8 + (l4 & 1) * 4] = q;            \
        }                                                                        \
    float* sR = (float*)sX;                                                      \
    {                                                                            \
        const float* wr = Wz + (size_t)tid * 32;                                 \
        float s = 0.f;                                                           \
        _Pragma("unroll")                                                        \
        for (int q = 0; q < 8; q++) {                                            \
            float4 v = ((const float4*)wr)[q];                                   \
            s += v.x + v.y + v.z + v.w;                                          \
        }                                                                        \
        sR[tid] = s;                                                             \
    }                                                                            \
    u16x8 wzf[4];                                                                \
    _Pragma("unroll")                                                            \
    for (int ot = 0; ot < 4; ot++) {                                             \
        const float* wr = Wz + (size_t)(w * 64 + ot * 16 + l15) * 32 + l4 * 8;   \
        float4 v0 = ((const float4*)wr)[0];                                      \
        float4 v1 = ((const float4*)wr)[1];                                      \
        uint4 q = { cvtpk(v0.x,v0.y), cvtpk(v0.z,v0.w),                          \
                    cvtpk(v1.x,v1.y), cvtpk(v1.z,v1.w) };                        \
        wzf[ot] = *(u16x8*)&q;                                                   \
    }                                                                            \
    __syncthreads();                                                             \
    float s = 0.f, s2a = 0.f;                                                    \
    f32x4 zero4 = {0.f, 0.f, 0.f, 0.f};                                          \
    _Pragma("unroll")                                                            \
    for (int ht = 0; ht < 4; ht++) {                                             \
        int row = ht * 16 + l15;                                                 \
        u16x8 bfr = *(const u16x8*)&sMain[row * 256 + (w * 4 + (l4 ^ (row & 3))) * 8]; \
        _Pragma("unroll")                                                        \
        for (int ot = 0; ot < 4; ot++) {                                         \
            f32x4 z = mfma16(wzf[ot], bfr, zero4);                               \
            f32x4 rv = *(const f32x4*)&sR[w * 64 + ot * 16 + l4 * 4];            \
            z = z + c0v * rv;                                                    \
            float* zp = zout + ((size_t)(b * 512 + w * 64 + ot * 16 + l4 * 4)) * 4096 \
                      + hw0 + ht * 16 + l15;                                     \
            _Pragma("unroll")                                                    \
            for (int r = 0; r < 4; r++) {                                        \
                zp[(size_t)r * 4096] = z[r];                                     \
                s += z[r]; s2a += z[r] * z[r];                                   \
            }                                                                    \
        }                                                                        \
    }                                                                            \
    _Pragma("unroll")                                                            \
    for (int m = 1; m < 64; m <<= 1) {                                           \
        s   += __shfl_xor(s, m);                                                 \
        s2a += __shfl_xor(s2a, m);                                               \
    }                                                                            \
    if (lane == 0) {                                                             \
        atomicAdd(&zstat[(size_t)(b * 8 + w) * 2 + 0], s);                       \
        atomicAdd(&zstat[(size_t)(b * 8 + w) * 2 + 1], s2a);                     \
    }

// ---------------------------------------------------------------------------
// k2 (gll path): Wt staged via global_load_lds from pre-swizzled bf16 wtb;
// raw-barrier pipeline with counted vmcnt so X prefetch survives the barrier.
// grid 1024 = (b:16, hwt:64), 512 threads, LDS 40 KB.
// ---------------------------------------------------------------------------
#define K2G_BODY(KC, VCUR, VNXT, DOPREF)                                         \
  {                                                                              \
    /* barrier1: protect LDS reuse; LDS-only drain (no vmem!) */                 \
    asm volatile("s_waitcnt lgkmcnt(0)" ::: "memory");                           \
    __builtin_amdgcn_s_barrier();                                                \
    __builtin_amdgcn_sched_barrier(0);                                           \
    /* X_k regs -> bf16 -> swizzled ds_write (compiler waits only X_k here) */   \
    {                                                                            \
        uint4 q = { cvtpk(VCUR[0],VCUR[1]), cvtpk(VCUR[2],VCUR[3]),              \
                    cvtpk(VCUR[4],VCUR[5]), cvtpk(VCUR[6],VCUR[7]) };            \
        int phys = w ^ (xrow & 7);                                               \
        *(uint4*)&sX[xrow * 64 + phys * 8] = q;                                  \
    }                                                                            \
    /* Wt chunk: 4 linear gll16 per thread (pre-swizzled source) */              \
    _Pragma("unroll")                                                            \
    for (int k = 0; k < 4; k++) {                                                \
        int u = k * 512 + tid;                                                   \
        gll16(wtb + (((size_t)(KC) * 2048 + u) << 3), &sMain[u << 3]);           \
    }                                                                            \
    /* issue next X chunk; stays in flight across the barrier */                 \
    if (DOPREF) {                                                                \
        const float* xc = xhi + ((size_t)b * 512 + ((KC) + 1) * 64 + w * 8) * 4096 + hw0 + xrow; \
        _Pragma("unroll")                                                        \
        for (int j = 0; j < 8; j++) VNXT[j] = xc[(size_t)j * 4096];              \
    }                                                                            \
    /* barrier2: wait gll (oldest 4) + ds_writes; leave 8 X loads in flight */   \
    if (DOPREF) { asm volatile("s_waitcnt vmcnt(8) lgkmcnt(0)" ::: "memory"); }  \
    else        { asm volatile("s_waitcnt vmcnt(0) lgkmcnt(0)" ::: "memory"); }  \
    __builtin_amdgcn_s_barrier();                                                \
    __builtin_amdgcn_sched_barrier(0);                                           \
    /* MFMA phase */                                                             \
    _Pragma("unroll")                                                            \
    for (int kk = 0; kk < 2; kk++) {                                             \
        u16x8 bf[4];                                                             \
        _Pragma("unroll")                                                        \
        for (int ht = 0; ht < 4; ht++) {                                         \
            int row = ht * 16 + l15;                                             \
            bf[ht] = *(const u16x8*)&sX[row * 64 + (((kk*4+l4) ^ (row&7)) << 3)]; \
        }                                                                        \
        _Pragma("unroll")                                                        \
        for (int i = 0; i < 2; i++) {                                            \
            int row = w * 32 + i * 16 + l15;                                     \
            u16x8 af = *(const u16x8*)&sMain[row * 64 + (((kk*4+l4) ^ (row&7)) << 3)]; \
            _Pragma("unroll")                                                    \
            for (int ht = 0; ht < 4; ht++)                                       \
                acc[i][ht] = mfma16(af, bf[ht], acc[i][ht]);                     \
        }                                                                        \
    }                                                                            \
  }

__global__ __launch_bounds__(512, 4)
void k2_main_g(const float* __restrict__ xhi, const unsigned short* __restrict__ wtb,
               const float* __restrict__ Wz, const float* __restrict__ coef,
               float* __restrict__ zout, float* __restrict__ zstat)
{
    __shared__ unsigned short sMain[16384];  // 32 KB: Wt chunk, then xx[64hw][256p]
    __shared__ unsigned short sX[4096];      // 8 KB: X tile; epilogue: float sR[512]

    int tid = threadIdx.x;
    int w = tid >> 6, lane = tid & 63;
    int l15 = lane & 15, l4 = lane >> 4;
    int hwt = blockIdx.x & 63, b = blockIdx.x >> 6;
    int hw0 = hwt * 64;
    int xrow = tid & 63;

    const float* cf = coef + (size_t)(b * 8 + w) * 3;
    float c0v = cf[0], c1v = cf[1], c2v = cf[2];

    f32x4 acc[2][4] = {};

    float vbA[8], vbB[8];
    {   // preload X chunk 0
        const float* xc = xhi + ((size_t)b * 512 + w * 8) * 4096 + hw0 + xrow;
#pragma unroll
        for (int j = 0; j < 8; j++) vbA[j] = xc[(size_t)j * 4096];
    }

    K2G_BODY(0, vbA, vbB, true);
    K2G_BODY(1, vbB, vbA, true);
    K2G_BODY(2, vbA, vbB, true);
    K2G_BODY(3, vbB, vbA, true);
    K2G_BODY(4, vbA, vbB, true);
    K2G_BODY(5, vbB, vbA, true);
    K2G_BODY(6, vbA, vbB, true);
    K2G_BODY(7, vbB, vbA, false);

    K2_EPILOGUE
}

// ---------------------------------------------------------------------------
// k2 fallback (r7 verbatim structure): used when ws_size < wtb requirement.
// ---------------------------------------------------------------------------
#define K2_BODY(C0, VCUR, VNXT, DOPREF)                                          \
  {                                                                              \
    if (DOPREF) {                                                                \
        const float* xc = xhi + ((size_t)b * 512 + (C0) + 64 + w * 8) * 4096 + hw0 + xrow; \
        _Pragma("unroll")                                                        \
        for (int j = 0; j < 8; j++) VNXT[j] = xc[(size_t)j * 4096];              \
    }                                                                            \
    __syncthreads();                                                             \
    _Pragma("unroll")                                                            \
    for (int k = 0; k < 4; k++) {                                                \
        int idx = k * 512 + tid;                                                 \
        int row = idx >> 3, s = idx & 7;                                         \
        const float* sp = Wt + (size_t)row * 512 + (C0) + s * 8;                 \
        float4 v0 = ((const float4*)sp)[0];                                      \
        float4 v1 = ((const float4*)sp)[1];                                      \
        uint4 q = { cvtpk(v0.x,v0.y), cvtpk(v0.z,v0.w),                          \
                    cvtpk(v1.x,v1.y), cvtpk(v1.z,v1.w) };                        \
        *(uint4*)&sMain[row * 64 + ((s ^ (row & 7)) << 3)] = q;                  \
    }                                                                            \
    {                                                                            \
        uint4 q = { cvtpk(VCUR[0],VCUR[1]), cvtpk(VCUR[2],VCUR[3]),              \
                    cvtpk(VCUR[4],VCUR[5]), cvtpk(VCUR[6],VCUR[7]) };            \
        int phys = w ^ (xrow & 7);                                               \
        *(uint4*)&sX[xrow * 64 + phys * 8] = q;                                  \
    }                                                                            \
    __syncthreads();                                                             \
    _Pragma("unroll")                                                            \
    for (int kk = 0; kk < 2; kk++) {                                             \
        u16x8 bf[4];                                                             \
        _Pragma("unroll")                                                        \
        for (int ht = 0; ht < 4; ht++) {                                         \
            int row = ht * 16 + l15;                                             \
            bf[ht] = *(const u16x8*)&sX[row * 64 + (((kk*4+l4) ^ (row&7)) << 3)]; \
        }                                                                        \
        _Pragma("unroll")                                                        \
        for (int i = 0; i < 2; i++) {                                            \
            int row = w * 32 + i * 16 + l15;                                     \
            u16x8 af = *(const u16x8*)&sMain[row * 64 + (((kk*4+l4) ^ (row&7)) << 3)]; \
            _Pragma("unroll")                                                    \
            for (int ht = 0; ht < 4; ht++)                                       \
                acc[i][ht] = mfma16(af, bf[ht], acc[i][ht]);                     \
        }                                                                        \
    }                                                                            \
  }

__global__ __launch_bounds__(512, 4)
void k2_main_fb(const float* __restrict__ xhi, const float* __restrict__ Wt,
                const float* __restrict__ Wz, const float* __restrict__ coef,
                float* __restrict__ zout, float* __restrict__ zstat)
{
    __shared__ unsigned short sMain[16384];
    __shared__ unsigned short sX[4096];

    int tid = threadIdx.x;
    int w = tid >> 6, lane = tid & 63;
    int l15 = lane & 15, l4 = lane >> 4;
    int hwt = blockIdx.x & 63, b = blockIdx.x >> 6;
    int hw0 = hwt * 64;
    int xrow = tid & 63;

    const float* cf = coef + (size_t)(b * 8 + w) * 3;
    float c0v = cf[0], c1v = cf[1], c2v = cf[2];

    f32x4 acc[2][4] = {};

    float vbA[8], vbB[8];
    {
        const float* xc = xhi + ((size_t)b * 512 + w * 8) * 4096 + hw0 + xrow;
#pragma unroll
        for (int j = 0; j < 8; j++) vbA[j] = xc[(size_t)j * 4096];
    }

    for (int kc2 = 0; kc2 < 4; kc2++) {
        int c0 = kc2 * 128;
        K2_BODY(c0,      vbA, vbB, true);
        K2_BODY(c0 + 64, vbB, vbA, (kc2 < 3));
    }

    K2_EPILOGUE
}

__global__ void k2b_gn(const float* __restrict__ zstat, float* __restrict__ gnstat)
{
    int t = threadIdx.x;
    if (t >= 128) return;
    float S = zstat[t * 2], S2 = zstat[t * 2 + 1];
    const float N = 64.0f * 4096.0f;
    float mean = S / N;
    float var = S2 / N - mean * mean;
    var = var < 0.f ? 0.f : var;
    gnstat[t * 2] = mean;
    gnstat[t * 2 + 1] = rsqrtf(var + EPS_);
}

// ---------------------------------------------------------------------------
// k3: out = (z - mean)*rsig*gn_w + gn_b + input_high  (in place on d_out)
// ---------------------------------------------------------------------------
__global__ __launch_bounds__(256)
void k3_final(float* __restrict__ out, const float* __restrict__ xhi,
              const float* __restrict__ gnstat, const float* __restrict__ gnw,
              const float* __restrict__ gnb)
{
#pragma unroll
    for (int k = 0; k < 4; k++) {
        size_t idx = (size_t)blockIdx.x * 1024 + (size_t)k * 256 + threadIdx.x;
        size_t e = idx * 4;
        int ch = (int)((e >> 12) & 511);
        int b  = (int)(e >> 21);
        int gg = ch >> 6;
        const float* gs = gnstat + (size_t)(b * 8 + gg) * 2;
        float mean = gs[0];
        float w = gnw[ch] * gs[1];
        float bb = gnb[ch];
        float4 z = ((const float4*)out)[idx];
        float4 xv = ((const float4*)xhi)[idx];
        float4 r;
        r.x = (z.x - mean) * w + bb + xv.x;
        r.y = (z.y - mean) * w + bb + xv.y;
        r.z = (z.z - mean) * w + bb + xv.z;
        r.w = (z.w - mean) * w + bb + xv.w;
        ((float4*)out)[idx] = r;
    }
}

extern "C" void kernel_launch(void* const* d_in, const int* in_sizes, int n_in,
                              void* d_out, int out_size, void* d_ws, size_t ws_size,
                              hipStream_t stream) {
    (void)in_sizes; (void)n_in; (void)out_size;
    const float* xhi = (const float*)d_in[0];
    const float* xlo = (const float*)d_in[1];
    const float* Wt  = (const float*)d_in[2];
    const float* Wp  = (const float*)d_in[3];
    const float* Wg  = (const float*)d_in[4];
    const float* Wz  = (const float*)d_in[5];
    const float* gnw = (const float*)d_in[6];
    const float* gnb = (const float*)d_in[7];
    float* out = (float*)d_out;
    float* ws  = (float*)d_ws;

    float* sxsum    = ws;              // 8192 floats
    float* att_part = ws + 8192;       // 8192
    float* coef     = ws + 16384;      // 384
    float* zstat    = ws + 16768;      // 256
    float* gnstat   = ws + 17024;      // 256   -> 17280 f = 69120 B
    unsigned short* wtb = (unsigned short*)((char*)d_ws + 69632);  // 262144 B

    const size_t WS_NEED = 69632 + 262144;   // 331776
    bool use_gll = (ws_size >= WS_NEED);

    double g2 = 2.0e-4;
    double ee = exp(-g2);
    float a0s = (float)ee;
    float a1s = (float)(g2 * ee);
    float a2s = (float)(g2 * g2 * 0.5 * ee);

    k0s     <<<dim3(256),  dim3(256), 0, stream>>>(xlo, sxsum);
    k1_att  <<<dim3(1024), dim3(256), 0, stream>>>(xlo, Wp, Wg, att_part);
    k1b_coef<<<dim3(128),  dim3(64),  0, stream>>>(Wg, sxsum, att_part, coef, a0s, a1s, a2s);
    hipMemsetAsync(zstat, 0, 256 * sizeof(float), stream);
    if (use_gll) {
        k0w_t    <<<dim3(64),   dim3(256), 0, stream>>>(Wt, wtb);
        k2_main_g<<<dim3(1024), dim3(512), 0, stream>>>(xhi, wtb, Wz, coef, out, zstat);
    } else {
        k2_main_fb<<<dim3(1024), dim3(512), 0, stream>>>(xhi, Wt, Wz, coef, out, zstat);
    }
    k2b_gn  <<<dim3(1),    dim3(128), 0, stream>>>(zstat, gnstat);
    k3_final<<<dim3(8192), dim3(256), 0, stream>>>(out, xhi, gnstat, gnw, gnb);
}